// Round 3
// baseline (1247.850 us; speedup 1.0000x reference)
//
#include <hip/hip_runtime.h>

#define NN 50000
#define NE 1600000
#define EPW 128                   // edges per wave in edge_aggr

// ---- workspace layout (element offsets) ----
// floats:
#define OF_X0    0
#define OF_X1    (OF_X0 + NN*16)              // 800000
#define OF_HAG   (OF_X1 + NN*16)              // 1600000
#define OF_MM    (OF_HAG + NN*64)             // 4800000
#define OF_C0    (OF_MM + 3*4*64)             // +768
#define OF_W1TN  (OF_C0 + 3*64)               // +192
#define OF_QW    (OF_W1TN + 3*64*32)          // +6144
#define OF_INT   (OF_QW + 8)
// ints (relative to OF_INT as int*):
#define WI_DEG   0
#define WI_CUR   (WI_DEG + NN)
#define WI_OFF   (WI_CUR + NN)                // NN+1
#define WI_SP    (WI_OFF + NN + 1)            // NE (src_s in gathered mode, perm otherwise)
#define WI_END   (WI_SP + NE)
// pa_s (gathered mode only), float4-aligned
#define OF_PAS   (((OF_INT + WI_END) + 3) & ~3)
#define OF_END_GATHERED   (OF_PAS + NE*4)
#define OF_END_FALLBACK   (OF_INT + WI_END)

// ---------------------------------------------------------------------------
// prep: fold edge-embedding into Mm[l][4][64] + c0[l][64], transpose node W1,
// collapse q weights. (edge W1 used directly from ew1, layout [32][64].)
// ---------------------------------------------------------------------------
__global__ void prep_kernel(const float* __restrict__ ew1, const float* __restrict__ eb1,
                            const float* __restrict__ nw1,
                            const float* __restrict__ eeW, const float* __restrict__ eeB,
                            const float* __restrict__ few, const float* __restrict__ feb,
                            float* __restrict__ Mm, float* __restrict__ c0,
                            float* __restrict__ w1tn, float* __restrict__ qw)
{
    int t = blockIdx.x * blockDim.x + threadIdx.x;
    int stride = gridDim.x * blockDim.x;
    for (int idx = t; idx < 3 * 64 * 32; idx += stride) {
        int l = idx / 2048, r = idx % 2048, j = r / 32, i = r % 32;
        w1tn[idx] = nw1[l * 2048 + i * 64 + j];   // node_mlp_w1 [3][32][64] -> [3][64][32]
    }
    // Mm[l][f][j] = sum_k eeW[f][k] * W1e[l][32+k][j]
    for (int idx = t; idx < 3 * 4 * 64; idx += stride) {
        int l = idx / 256, r = idx % 256, f = r / 64, j = r % 64;
        float s = 0.f;
        for (int k = 0; k < 16; k++) s += eeW[f * 16 + k] * ew1[l * 3072 + (32 + k) * 64 + j];
        Mm[idx] = s;
    }
    // c0[l][j] = b1[l][j] + sum_k eeB[k] * W1e[l][32+k][j]
    for (int idx = t; idx < 3 * 64; idx += stride) {
        int l = idx / 64, j = idx % 64;
        float s = eb1[idx];
        for (int k = 0; k < 16; k++) s += eeB[k] * ew1[l * 3072 + (32 + k) * 64 + j];
        c0[idx] = s;
    }
    if (t < 4) {
        float s = 0.f;
        for (int k = 0; k < 16; k++) s += eeW[t * 16 + k] * few[k];
        qw[t] = s;
    } else if (t == 4) {
        float s = feb[0];
        for (int k = 0; k < 16; k++) s += eeB[k] * few[k];
        qw[4] = s;
    }
}

// ---------------------------------------------------------------------------
// node init: x0 = leak*w+b ; zero deg, cursor, hag[N][64]
// ---------------------------------------------------------------------------
__global__ __launch_bounds__(256) void node_init_kernel(
    const float* __restrict__ leak, const float* __restrict__ nw, const float* __restrict__ nb,
    float* __restrict__ x0, float* __restrict__ hag, int* __restrict__ deg, int* __restrict__ cur)
{
    int n = blockIdx.x * blockDim.x + threadIdx.x;
    if (n >= NN) return;
    float la = leak[n];
    float4* xo = reinterpret_cast<float4*>(x0 + n * 16);
    #pragma unroll
    for (int q4 = 0; q4 < 4; q4++) {
        float4 v;
        v.x = la * nw[q4 * 4 + 0] + nb[q4 * 4 + 0];
        v.y = la * nw[q4 * 4 + 1] + nb[q4 * 4 + 1];
        v.z = la * nw[q4 * 4 + 2] + nb[q4 * 4 + 2];
        v.w = la * nw[q4 * 4 + 3] + nb[q4 * 4 + 3];
        xo[q4] = v;
    }
    deg[n] = 0;
    cur[n] = 0;
    float4 z = {0.f, 0.f, 0.f, 0.f};
    float4* hp = reinterpret_cast<float4*>(hag + n * 64);
    #pragma unroll
    for (int j = 0; j < 16; j++) hp[j] = z;
}

// ---------------------------------------------------------------------------
// edge init: q output (collapsed linear) + int degree histogram
// ---------------------------------------------------------------------------
__global__ __launch_bounds__(256) void edge_init_kernel(
    const float* __restrict__ pa, const int* __restrict__ dst,
    const float* __restrict__ qw, float* __restrict__ qout, int* __restrict__ deg)
{
    int t = blockIdx.x * blockDim.x + threadIdx.x;
    if (t >= NE) return;
    float4 p = reinterpret_cast<const float4*>(pa)[t];
    qout[t] = qw[4] + p.x * qw[0] + p.y * qw[1] + p.z * qw[2] + p.w * qw[3];
    atomicAdd(&deg[dst[t]], 1);
}

// ---------------------------------------------------------------------------
// single-block exclusive scan of deg[NN] -> off[NN+1]
// ---------------------------------------------------------------------------
#define SCAN_T 1024
#define SCAN_C 49
__global__ __launch_bounds__(SCAN_T) void scan_kernel(const int* __restrict__ deg, int* __restrict__ off)
{
    __shared__ int part[SCAN_T];
    int tid = threadIdx.x;
    int base = tid * SCAN_C;
    int s = 0;
    for (int i = 0; i < SCAN_C; i++) {
        int idx = base + i;
        if (idx < NN) s += deg[idx];
    }
    part[tid] = s;
    __syncthreads();
    for (int o = 1; o < SCAN_T; o <<= 1) {
        int v = (tid >= o) ? part[tid - o] : 0;
        __syncthreads();
        part[tid] += v;
        __syncthreads();
    }
    int run = part[tid] - s;
    for (int i = 0; i < SCAN_C; i++) {
        int idx = base + i;
        if (idx < NN) { off[idx] = run; run += deg[idx]; }
    }
    if (tid == SCAN_T - 1) off[NN] = part[SCAN_T - 1];
}

// ---------------------------------------------------------------------------
// scatter into dst-sorted order. GATHERED: emit src_s + pa_s; else perm.
// ---------------------------------------------------------------------------
template<int GATHERED>
__global__ __launch_bounds__(256) void scatter_kernel(
    const int* __restrict__ ei, const float* __restrict__ pa,
    const int* __restrict__ off, int* __restrict__ cur,
    int* __restrict__ sp, float* __restrict__ pa_s)
{
    int t = blockIdx.x * blockDim.x + threadIdx.x;
    if (t >= NE) return;
    int d = ei[NE + t];
    int pos = off[d] + atomicAdd(&cur[d], 1);
    if (GATHERED) {
        sp[pos] = ei[t];
        reinterpret_cast<float4*>(pa_s)[pos] = reinterpret_cast<const float4*>(pa)[t];
    } else {
        sp[pos] = t;
    }
}

// ---------------------------------------------------------------------------
// edge MLP stage-1 + segmented aggregation, wave-cooperative.
// lane j owns hidden unit j; a wave walks EPW contiguous dst-sorted edges.
// Per segment: hd (dst dot, uniform s_loads) computed once; per edge:
// 16 src FMAs + 4 pa FMAs + relu + acc. Flush acc with one coalesced
// 64-lane atomic per segment.
// ---------------------------------------------------------------------------
template<int GATHERED>
__global__ __launch_bounds__(256) void edge_aggr_kernel(
    const float* __restrict__ x,
    const int* __restrict__ sp, const float* __restrict__ pa_s,
    const int* __restrict__ ei, const float* __restrict__ pa,
    const int* __restrict__ off,
    const float* __restrict__ w1,   // ew1 + l*3072, [32][64]
    const float* __restrict__ Mm,   // [4][64]
    const float* __restrict__ c0,   // [64]
    float* __restrict__ hag)
{
    int lane = threadIdx.x & 63;
    int wave = (blockIdx.x * blockDim.x + threadIdx.x) >> 6;
    int e0 = wave * EPW;
    if (e0 >= NE) return;
    int e1 = e0 + EPW; if (e1 > NE) e1 = NE;

    float w1r[32];
    #pragma unroll
    for (int i = 0; i < 32; i++) w1r[i] = w1[i * 64 + lane];
    float m0 = Mm[lane], m1 = Mm[64 + lane], m2 = Mm[128 + lane], m3 = Mm[192 + lane];
    float c0r = c0[lane];

    // binary search: largest d with off[d] <= e0
    int lo = 0, hi = NN;
    while (hi - lo > 1) {
        int mid = (lo + hi) >> 1;
        if (off[mid] <= e0) lo = mid; else hi = mid;
    }
    int d = lo;
    int e = e0;
    while (e < e1) {
        int segend = off[d + 1];
        while (segend <= e) { ++d; segend = off[d + 1]; }
        // per-segment dst contribution (wave-uniform scalar loads)
        const float* xd = x + d * 16;
        float hd0 = c0r, hd1 = 0.f;
        #pragma unroll
        for (int i = 0; i < 8; i++)  hd0 += xd[i] * w1r[i];
        #pragma unroll
        for (int i = 8; i < 16; i++) hd1 += xd[i] * w1r[i];
        float hd = hd0 + hd1;
        int eend = segend < e1 ? segend : e1;
        float acc = 0.f;
        for (; e < eend; ++e) {
            int s; float4 p;
            if (GATHERED) {
                s = sp[e];
                p = reinterpret_cast<const float4*>(pa_s)[e];
            } else {
                int t = sp[e];
                s = ei[t];
                p = reinterpret_cast<const float4*>(pa)[t];
            }
            const float* xs = x + s * 16;
            float h0 = hd + p.x * m0 + p.y * m1;
            float h1 = p.z * m2 + p.w * m3;
            #pragma unroll
            for (int i = 0; i < 8; i++)  h0 += xs[i] * w1r[16 + i];
            #pragma unroll
            for (int i = 8; i < 16; i++) h1 += xs[i] * w1r[24 + i - 8];
            float h = fmaxf(h0 + h1, 0.f);
            acc += h;
        }
        unsafeAtomicAdd(&hag[d * 64 + lane], acc);
        ++d;
    }
}

// ---------------------------------------------------------------------------
// node update: aggr = W2^T(hag)/deg + b2 (0 if deg==0), then 32->64->16 MLP.
// Re-zeros hag for the next layer. Emits H on last layer.
// ---------------------------------------------------------------------------
__global__ __launch_bounds__(256) void node_mlp_kernel(
    const float* __restrict__ x, float* __restrict__ xn,
    float* __restrict__ hag, const int* __restrict__ off,
    const float* __restrict__ ew2, const float* __restrict__ eb2,
    const float* __restrict__ nw1t, const float* __restrict__ nb1,
    const float* __restrict__ nw2, const float* __restrict__ nb2,
    const float* __restrict__ fnw, const float* __restrict__ fnb,
    float* __restrict__ Hout, int writeH)
{
    int n = blockIdx.x * blockDim.x + threadIdx.x;
    if (n >= NN) return;
    float u[32];
    const float4* xp = reinterpret_cast<const float4*>(x + n * 16);
    #pragma unroll
    for (int q4 = 0; q4 < 4; q4++) {
        float4 v = xp[q4];
        u[q4 * 4 + 0] = v.x; u[q4 * 4 + 1] = v.y; u[q4 * 4 + 2] = v.z; u[q4 * 4 + 3] = v.w;
    }
    int dg = off[n + 1] - off[n];
    float inv = 1.0f / (float)(dg > 0 ? dg : 1);
    float bsc = (dg > 0) ? 1.0f : 0.0f;
    float tacc[16];
    #pragma unroll
    for (int k = 0; k < 16; k++) tacc[k] = 0.f;
    float4* hp4 = reinterpret_cast<float4*>(hag + n * 64);
    #pragma unroll 1
    for (int j4 = 0; j4 < 16; j4++) {
        float4 hv = hp4[j4];
        int j = j4 * 4;
        #pragma unroll
        for (int k = 0; k < 16; k++) {
            tacc[k] += hv.x * ew2[(j + 0) * 16 + k];
            tacc[k] += hv.y * ew2[(j + 1) * 16 + k];
            tacc[k] += hv.z * ew2[(j + 2) * 16 + k];
            tacc[k] += hv.w * ew2[(j + 3) * 16 + k];
        }
    }
    float4 z = {0.f, 0.f, 0.f, 0.f};
    #pragma unroll
    for (int j4 = 0; j4 < 16; j4++) hp4[j4] = z;   // re-zero for next layer
    #pragma unroll
    for (int k = 0; k < 16; k++) u[16 + k] = bsc * eb2[k] + tacc[k] * inv;

    float o[16];
    #pragma unroll
    for (int k = 0; k < 16; k++) o[k] = nb2[k];
    #pragma unroll 1
    for (int j = 0; j < 64; j++) {
        float h = nb1[j];
        const float* wr = nw1t + j * 32;
        #pragma unroll
        for (int i = 0; i < 32; i++) h += u[i] * wr[i];
        h = fmaxf(h, 0.f);
        #pragma unroll
        for (int k = 0; k < 16; k++) o[k] += h * nw2[j * 16 + k];
    }
    float4* xo = reinterpret_cast<float4*>(xn + n * 16);
    #pragma unroll
    for (int q4 = 0; q4 < 4; q4++) {
        float4 v;
        v.x = o[q4 * 4 + 0]; v.y = o[q4 * 4 + 1]; v.z = o[q4 * 4 + 2]; v.w = o[q4 * 4 + 3];
        xo[q4] = v;
    }
    if (writeH) {
        float s = fnb[0];
        #pragma unroll
        for (int k = 0; k < 16; k++) s += o[k] * fnw[k];
        Hout[n] = s;
    }
}

extern "C" void kernel_launch(void* const* d_in, const int* in_sizes, int n_in,
                              void* d_out, int out_size, void* d_ws, size_t ws_size,
                              hipStream_t stream)
{
    const float* leak = (const float*)d_in[0];
    const float* pa   = (const float*)d_in[1];
    const int*   ei   = (const int*)d_in[2];
    const float* neww = (const float*)d_in[3];
    const float* newb = (const float*)d_in[4];
    const float* eeW  = (const float*)d_in[5];
    const float* eeB  = (const float*)d_in[6];
    const float* ew1  = (const float*)d_in[7];
    const float* eb1  = (const float*)d_in[8];
    const float* ew2  = (const float*)d_in[9];
    const float* eb2  = (const float*)d_in[10];
    const float* nw1  = (const float*)d_in[11];
    const float* nb1  = (const float*)d_in[12];
    const float* nw2  = (const float*)d_in[13];
    const float* nb2  = (const float*)d_in[14];
    const float* fnw  = (const float*)d_in[15];
    const float* fnb  = (const float*)d_in[16];
    const float* few  = (const float*)d_in[17];
    const float* feb  = (const float*)d_in[18];

    float* ws   = (float*)d_ws;
    float* x0   = ws + OF_X0;
    float* x1   = ws + OF_X1;
    float* hag  = ws + OF_HAG;
    float* Mm   = ws + OF_MM;
    float* c0   = ws + OF_C0;
    float* w1tn = ws + OF_W1TN;
    float* qw   = ws + OF_QW;
    int*   wi   = (int*)(ws + OF_INT);
    int*   deg  = wi + WI_DEG;
    int*   cur  = wi + WI_CUR;
    int*   off  = wi + WI_OFF;
    int*   sp   = wi + WI_SP;
    float* pa_s = ws + OF_PAS;

    int gathered = (ws_size >= (size_t)OF_END_GATHERED * sizeof(float)) ? 1 : 0;

    float* H = (float*)d_out;
    float* q = (float*)d_out + NN;
    const int* dstp = ei + NE;

    prep_kernel<<<8, 256, 0, stream>>>(ew1, eb1, nw1, eeW, eeB, few, feb,
                                       Mm, c0, w1tn, qw);
    node_init_kernel<<<(NN + 255) / 256, 256, 0, stream>>>(leak, neww, newb, x0, hag, deg, cur);
    edge_init_kernel<<<(NE + 255) / 256, 256, 0, stream>>>(pa, dstp, qw, q, deg);
    scan_kernel<<<1, SCAN_T, 0, stream>>>(deg, off);
    if (gathered)
        scatter_kernel<1><<<(NE + 255) / 256, 256, 0, stream>>>(ei, pa, off, cur, sp, pa_s);
    else
        scatter_kernel<0><<<(NE + 255) / 256, 256, 0, stream>>>(ei, pa, off, cur, sp, pa_s);

    int nwaves = (NE + EPW - 1) / EPW;          // 12500
    int eblocks = (nwaves * 64 + 255) / 256;    // 3125

    float* xcur = x0;
    float* xnxt = x1;
    for (int l = 0; l < 3; l++) {
        if (gathered)
            edge_aggr_kernel<1><<<eblocks, 256, 0, stream>>>(
                xcur, sp, pa_s, ei, pa, off, ew1 + l * 3072, Mm + l * 256, c0 + l * 64, hag);
        else
            edge_aggr_kernel<0><<<eblocks, 256, 0, stream>>>(
                xcur, sp, pa_s, ei, pa, off, ew1 + l * 3072, Mm + l * 256, c0 + l * 64, hag);
        node_mlp_kernel<<<(NN + 255) / 256, 256, 0, stream>>>(
            xcur, xnxt, hag, off, ew2 + l * 1024, eb2 + l * 16,
            w1tn + l * 2048, nb1 + l * 64, nw2 + l * 1024, nb2 + l * 16,
            fnw, fnb, H, (l == 2) ? 1 : 0);
        float* tmp = xcur; xcur = xnxt; xnxt = tmp;
    }
}

// Round 4
// 796.357 us; speedup vs baseline: 1.5669x; 1.5669x over previous
//
#include <hip/hip_runtime.h>

#define NN 50000
#define NE 1600000

// ---- workspace layout (element offsets) ----
// floats:
#define OF_X0    0
#define OF_X1    (OF_X0 + NN*16)              // 800000
#define OF_AGGR  (OF_X1 + NN*16)              // 1600000
#define OF_W1TE  (OF_AGGR + NN*16)            // 2400000
#define OF_MM    (OF_W1TE + 3*64*32)          // +6144
#define OF_C0    (OF_MM + 3*64*4)             // +768
#define OF_W1TN  (OF_C0 + 3*64)               // +192
#define OF_QW    (OF_W1TN + 3*64*32)          // +6144
#define OF_INT   (OF_QW + 8)
// ints (relative to OF_INT as int*):
#define WI_DEG   0
#define WI_CUR   (WI_DEG + NN)
#define WI_OFF   (WI_CUR + NN)                // NN+1
#define WI_SRC   (WI_OFF + NN + 1)            // NE (src_s gathered / perm fallback)
#define WI_DST   (WI_SRC + NE)                // NE (gathered only)
#define WI_END_G (WI_DST + NE)
#define WI_END_F (WI_DST)
// pa_s (gathered mode only), float4-aligned
#define OF_PAS   (((OF_INT + WI_END_G) + 3) & ~3)
#define OF_END_GATHERED   (OF_PAS + NE*4)

// ---------------------------------------------------------------------------
// prep: transpose per-layer W1 (edge rows 0..31 -> [64][32]; node [32][64] ->
// [64][32]), fold edge-embedding into Mm[l][64][4] + c0[l][64], collapse q.
// ---------------------------------------------------------------------------
__global__ void prep_kernel(const float* __restrict__ ew1, const float* __restrict__ eb1,
                            const float* __restrict__ nw1,
                            const float* __restrict__ eeW, const float* __restrict__ eeB,
                            const float* __restrict__ few, const float* __restrict__ feb,
                            float* __restrict__ w1te, float* __restrict__ Mm,
                            float* __restrict__ c0, float* __restrict__ w1tn,
                            float* __restrict__ qw)
{
    int t = blockIdx.x * blockDim.x + threadIdx.x;
    int stride = gridDim.x * blockDim.x;
    for (int idx = t; idx < 3 * 64 * 32; idx += stride) {
        int l = idx / 2048, r = idx % 2048, j = r / 32, i = r % 32;
        w1te[idx] = ew1[l * 3072 + i * 64 + j];   // edge_mlp_w1 [3][48][64], rows 0..31
        w1tn[idx] = nw1[l * 2048 + i * 64 + j];   // node_mlp_w1 [3][32][64]
    }
    // Mm[l][j][f] = sum_k eeW[f][k] * W1e[l][32+k][j]
    for (int idx = t; idx < 3 * 64 * 4; idx += stride) {
        int l = idx / 256, r = idx % 256, j = r / 4, f = r % 4;
        float s = 0.f;
        for (int k = 0; k < 16; k++) s += eeW[f * 16 + k] * ew1[l * 3072 + (32 + k) * 64 + j];
        Mm[idx] = s;
    }
    for (int idx = t; idx < 3 * 64; idx += stride) {
        int l = idx / 64, j = idx % 64;
        float s = eb1[idx];
        for (int k = 0; k < 16; k++) s += eeB[k] * ew1[l * 3072 + (32 + k) * 64 + j];
        c0[idx] = s;
    }
    if (t < 4) {
        float s = 0.f;
        for (int k = 0; k < 16; k++) s += eeW[t * 16 + k] * few[k];
        qw[t] = s;
    } else if (t == 4) {
        float s = feb[0];
        for (int k = 0; k < 16; k++) s += eeB[k] * few[k];
        qw[4] = s;
    }
}

// ---------------------------------------------------------------------------
// node init: x0 = leak*w+b ; zero deg, cursor, aggr
// ---------------------------------------------------------------------------
__global__ __launch_bounds__(256) void node_init_kernel(
    const float* __restrict__ leak, const float* __restrict__ nw, const float* __restrict__ nb,
    float* __restrict__ x0, float* __restrict__ aggr, int* __restrict__ deg, int* __restrict__ cur)
{
    int n = blockIdx.x * blockDim.x + threadIdx.x;
    if (n >= NN) return;
    float la = leak[n];
    float4* xo = reinterpret_cast<float4*>(x0 + n * 16);
    #pragma unroll
    for (int q4 = 0; q4 < 4; q4++) {
        float4 v;
        v.x = la * nw[q4 * 4 + 0] + nb[q4 * 4 + 0];
        v.y = la * nw[q4 * 4 + 1] + nb[q4 * 4 + 1];
        v.z = la * nw[q4 * 4 + 2] + nb[q4 * 4 + 2];
        v.w = la * nw[q4 * 4 + 3] + nb[q4 * 4 + 3];
        xo[q4] = v;
    }
    deg[n] = 0;
    cur[n] = 0;
    float4 z = {0.f, 0.f, 0.f, 0.f};
    float4* ap = reinterpret_cast<float4*>(aggr + n * 16);
    #pragma unroll
    for (int j = 0; j < 4; j++) ap[j] = z;
}

// ---------------------------------------------------------------------------
// edge init: q output (collapsed linear) + int degree histogram
// ---------------------------------------------------------------------------
__global__ __launch_bounds__(256) void edge_init_kernel(
    const float* __restrict__ pa, const int* __restrict__ dst,
    const float* __restrict__ qw, float* __restrict__ qout, int* __restrict__ deg)
{
    int t = blockIdx.x * blockDim.x + threadIdx.x;
    if (t >= NE) return;
    float4 p = reinterpret_cast<const float4*>(pa)[t];
    qout[t] = qw[4] + p.x * qw[0] + p.y * qw[1] + p.z * qw[2] + p.w * qw[3];
    atomicAdd(&deg[dst[t]], 1);
}

// ---------------------------------------------------------------------------
// single-block exclusive scan of deg[NN] -> off[NN+1]
// ---------------------------------------------------------------------------
#define SCAN_T 1024
#define SCAN_C 49
__global__ __launch_bounds__(SCAN_T) void scan_kernel(const int* __restrict__ deg, int* __restrict__ off)
{
    __shared__ int part[SCAN_T];
    int tid = threadIdx.x;
    int base = tid * SCAN_C;
    int s = 0;
    for (int i = 0; i < SCAN_C; i++) {
        int idx = base + i;
        if (idx < NN) s += deg[idx];
    }
    part[tid] = s;
    __syncthreads();
    for (int o = 1; o < SCAN_T; o <<= 1) {
        int v = (tid >= o) ? part[tid - o] : 0;
        __syncthreads();
        part[tid] += v;
        __syncthreads();
    }
    int run = part[tid] - s;
    for (int i = 0; i < SCAN_C; i++) {
        int idx = base + i;
        if (idx < NN) { off[idx] = run; run += deg[idx]; }
    }
    if (tid == SCAN_T - 1) off[NN] = part[SCAN_T - 1];
}

// ---------------------------------------------------------------------------
// scatter into dst-sorted order. GATHERED: emit src_s + dst_s + pa_s; else perm.
// ---------------------------------------------------------------------------
template<int GATHERED>
__global__ __launch_bounds__(256) void scatter_kernel(
    const int* __restrict__ ei, const float* __restrict__ pa,
    const int* __restrict__ off, int* __restrict__ cur,
    int* __restrict__ src_s, int* __restrict__ dst_s, float* __restrict__ pa_s)
{
    int t = blockIdx.x * blockDim.x + threadIdx.x;
    if (t >= NE) return;
    int d = ei[NE + t];
    int pos = off[d] + atomicAdd(&cur[d], 1);
    if (GATHERED) {
        src_s[pos] = ei[t];
        dst_s[pos] = d;
        reinterpret_cast<float4*>(pa_s)[pos] = reinterpret_cast<const float4*>(pa)[t];
    } else {
        src_s[pos] = t;   // perm
    }
}

// ---------------------------------------------------------------------------
// fused edge MLP + segmented aggregation, thread-per-edge over dst-sorted
// edges. Phase 1: msg[16] = W2^T relu(W1*[xd,xs] + Mm*pa + c0) -> LDS.
// Phase 2: block-local segment sums; one f32 atomic partial per (node,k).
// __launch_bounds__(256,4): allow ~128 VGPRs so m[32]+msg[16] stay in regs.
// ---------------------------------------------------------------------------
template<int GATHERED>
__global__ __launch_bounds__(256, 4) void edge_aggr_kernel(
    const float* __restrict__ x,
    const int* __restrict__ src_s, const int* __restrict__ dst_s,
    const float* __restrict__ pa_s,
    const int* __restrict__ ei, const float* __restrict__ pa,
    const int* __restrict__ off,
    const float* __restrict__ w1t,  // [64][32]
    const float* __restrict__ Mm,   // [64][4]
    const float* __restrict__ c0,   // [64]
    const float* __restrict__ w2,   // [64][16]
    float* __restrict__ aggr)
{
    __shared__ float smsg[256 * 17];
    __shared__ int sdst[256];
    int tid = threadIdx.x;
    int ebase = blockIdx.x * 256;
    int e = ebase + tid;            // NE is an exact multiple of 256

    int s, d; float4 p;
    if (GATHERED) {
        s = src_s[e];
        d = dst_s[e];
        p = reinterpret_cast<const float4*>(pa_s)[e];
    } else {
        int t = src_s[e];           // perm
        s = ei[t];
        d = ei[NE + t];
        p = reinterpret_cast<const float4*>(pa)[t];
    }
    sdst[tid] = d;

    float m[32];
    const float4* xd = reinterpret_cast<const float4*>(x + d * 16);
    const float4* xs = reinterpret_cast<const float4*>(x + s * 16);
    #pragma unroll
    for (int q4 = 0; q4 < 4; q4++) {
        float4 v = xd[q4];
        m[q4 * 4 + 0] = v.x; m[q4 * 4 + 1] = v.y; m[q4 * 4 + 2] = v.z; m[q4 * 4 + 3] = v.w;
    }
    #pragma unroll
    for (int q4 = 0; q4 < 4; q4++) {
        float4 v = xs[q4];
        m[16 + q4 * 4 + 0] = v.x; m[16 + q4 * 4 + 1] = v.y; m[16 + q4 * 4 + 2] = v.z; m[16 + q4 * 4 + 3] = v.w;
    }

    float msg[16];
    #pragma unroll
    for (int k = 0; k < 16; k++) msg[k] = 0.f;

    #pragma unroll 1
    for (int j0 = 0; j0 < 64; j0 += 8) {
        #pragma unroll
        for (int jj = 0; jj < 8; jj++) {
            int j = j0 + jj;
            float acc = c0[j] + p.x * Mm[j * 4 + 0] + p.y * Mm[j * 4 + 1]
                              + p.z * Mm[j * 4 + 2] + p.w * Mm[j * 4 + 3];
            const float* wr = w1t + j * 32;
            #pragma unroll
            for (int i = 0; i < 32; i++) acc += m[i] * wr[i];
            acc = fmaxf(acc, 0.f);
            const float* w2r = w2 + j * 16;
            #pragma unroll
            for (int k = 0; k < 16; k++) msg[k] += acc * w2r[k];
        }
    }
    #pragma unroll
    for (int k = 0; k < 16; k++) smsg[tid * 17 + k] = msg[k];
    __syncthreads();

    // phase 2: segmented reduction within the block
    int d_lo = sdst[0];
    int d_hi = sdst[255];
    int k = tid & 15;
    for (int n = d_lo + (tid >> 4); n <= d_hi; n += 16) {
        int s0 = off[n];
        int e0 = off[n + 1];
        if (s0 < ebase) s0 = ebase;
        if (e0 > ebase + 256) e0 = ebase + 256;
        if (s0 < e0) {
            float acc = 0.f;
            for (int i = s0; i < e0; i++) acc += smsg[(i - ebase) * 17 + k];
            unsafeAtomicAdd(&aggr[n * 16 + k], acc);
        }
    }
}

// ---------------------------------------------------------------------------
// node update: u = [x, aggr/deg + b2 (0 if deg==0)], MLP 32->64->16.
// Re-zeros aggr for the next layer. Emits H on last layer.
// ---------------------------------------------------------------------------
__global__ __launch_bounds__(256, 4) void node_mlp_kernel(
    const float* __restrict__ x, float* __restrict__ xn,
    float* __restrict__ aggr, const int* __restrict__ off,
    const float* __restrict__ eb2,
    const float* __restrict__ nw1t, const float* __restrict__ nb1,
    const float* __restrict__ nw2, const float* __restrict__ nb2,
    const float* __restrict__ fnw, const float* __restrict__ fnb,
    float* __restrict__ Hout, int writeH)
{
    int n = blockIdx.x * blockDim.x + threadIdx.x;
    if (n >= NN) return;
    float u[32];
    const float4* xp = reinterpret_cast<const float4*>(x + n * 16);
    #pragma unroll
    for (int q4 = 0; q4 < 4; q4++) {
        float4 v = xp[q4];
        u[q4 * 4 + 0] = v.x; u[q4 * 4 + 1] = v.y; u[q4 * 4 + 2] = v.z; u[q4 * 4 + 3] = v.w;
    }
    int dg = off[n + 1] - off[n];
    float inv = 1.0f / (float)(dg > 0 ? dg : 1);
    float bsc = (dg > 0) ? 1.0f : 0.0f;
    float4* ap = reinterpret_cast<float4*>(aggr + n * 16);
    float4 z = {0.f, 0.f, 0.f, 0.f};
    #pragma unroll
    for (int q4 = 0; q4 < 4; q4++) {
        float4 av = ap[q4];
        u[16 + q4 * 4 + 0] = av.x * inv + bsc * eb2[q4 * 4 + 0];
        u[16 + q4 * 4 + 1] = av.y * inv + bsc * eb2[q4 * 4 + 1];
        u[16 + q4 * 4 + 2] = av.z * inv + bsc * eb2[q4 * 4 + 2];
        u[16 + q4 * 4 + 3] = av.w * inv + bsc * eb2[q4 * 4 + 3];
        ap[q4] = z;   // re-zero for next layer
    }

    float o[16];
    #pragma unroll
    for (int k = 0; k < 16; k++) o[k] = nb2[k];
    #pragma unroll 1
    for (int j = 0; j < 64; j++) {
        float h = nb1[j];
        const float* wr = nw1t + j * 32;
        #pragma unroll
        for (int i = 0; i < 32; i++) h += u[i] * wr[i];
        h = fmaxf(h, 0.f);
        #pragma unroll
        for (int k = 0; k < 16; k++) o[k] += h * nw2[j * 16 + k];
    }
    float4* xo = reinterpret_cast<float4*>(xn + n * 16);
    #pragma unroll
    for (int q4 = 0; q4 < 4; q4++) {
        float4 v;
        v.x = o[q4 * 4 + 0]; v.y = o[q4 * 4 + 1]; v.z = o[q4 * 4 + 2]; v.w = o[q4 * 4 + 3];
        xo[q4] = v;
    }
    if (writeH) {
        float s = fnb[0];
        #pragma unroll
        for (int k = 0; k < 16; k++) s += o[k] * fnw[k];
        Hout[n] = s;
    }
}

extern "C" void kernel_launch(void* const* d_in, const int* in_sizes, int n_in,
                              void* d_out, int out_size, void* d_ws, size_t ws_size,
                              hipStream_t stream)
{
    const float* leak = (const float*)d_in[0];
    const float* pa   = (const float*)d_in[1];
    const int*   ei   = (const int*)d_in[2];
    const float* neww = (const float*)d_in[3];
    const float* newb = (const float*)d_in[4];
    const float* eeW  = (const float*)d_in[5];
    const float* eeB  = (const float*)d_in[6];
    const float* ew1  = (const float*)d_in[7];
    const float* eb1  = (const float*)d_in[8];
    const float* ew2  = (const float*)d_in[9];
    const float* eb2  = (const float*)d_in[10];
    const float* nw1  = (const float*)d_in[11];
    const float* nb1  = (const float*)d_in[12];
    const float* nw2  = (const float*)d_in[13];
    const float* nb2  = (const float*)d_in[14];
    const float* fnw  = (const float*)d_in[15];
    const float* fnb  = (const float*)d_in[16];
    const float* few  = (const float*)d_in[17];
    const float* feb  = (const float*)d_in[18];

    float* ws   = (float*)d_ws;
    float* x0   = ws + OF_X0;
    float* x1   = ws + OF_X1;
    float* aggr = ws + OF_AGGR;
    float* w1te = ws + OF_W1TE;
    float* Mm   = ws + OF_MM;
    float* c0   = ws + OF_C0;
    float* w1tn = ws + OF_W1TN;
    float* qw   = ws + OF_QW;
    int*   wi   = (int*)(ws + OF_INT);
    int*   deg  = wi + WI_DEG;
    int*   cur  = wi + WI_CUR;
    int*   off  = wi + WI_OFF;
    int*   srcs = wi + WI_SRC;
    int*   dsts = wi + WI_DST;
    float* pa_s = ws + OF_PAS;

    int gathered = (ws_size >= (size_t)OF_END_GATHERED * sizeof(float)) ? 1 : 0;

    float* H = (float*)d_out;
    float* q = (float*)d_out + NN;
    const int* dstp = ei + NE;

    prep_kernel<<<8, 256, 0, stream>>>(ew1, eb1, nw1, eeW, eeB, few, feb,
                                       w1te, Mm, c0, w1tn, qw);
    node_init_kernel<<<(NN + 255) / 256, 256, 0, stream>>>(leak, neww, newb, x0, aggr, deg, cur);
    edge_init_kernel<<<(NE + 255) / 256, 256, 0, stream>>>(pa, dstp, qw, q, deg);
    scan_kernel<<<1, SCAN_T, 0, stream>>>(deg, off);
    if (gathered)
        scatter_kernel<1><<<(NE + 255) / 256, 256, 0, stream>>>(ei, pa, off, cur, srcs, dsts, pa_s);
    else
        scatter_kernel<0><<<(NE + 255) / 256, 256, 0, stream>>>(ei, pa, off, cur, srcs, dsts, pa_s);

    float* xcur = x0;
    float* xnxt = x1;
    for (int l = 0; l < 3; l++) {
        if (gathered)
            edge_aggr_kernel<1><<<NE / 256, 256, 0, stream>>>(
                xcur, srcs, dsts, pa_s, ei, pa, off,
                w1te + l * 2048, Mm + l * 256, c0 + l * 64, ew2 + l * 1024, aggr);
        else
            edge_aggr_kernel<0><<<NE / 256, 256, 0, stream>>>(
                xcur, srcs, dsts, pa_s, ei, pa, off,
                w1te + l * 2048, Mm + l * 256, c0 + l * 64, ew2 + l * 1024, aggr);
        node_mlp_kernel<<<(NN + 255) / 256, 256, 0, stream>>>(
            xcur, xnxt, aggr, off, eb2 + l * 16,
            w1tn + l * 2048, nb1 + l * 64, nw2 + l * 1024, nb2 + l * 16,
            fnw, fnb, H, (l == 2) ? 1 : 0);
        float* tmp = xcur; xcur = xnxt; xnxt = tmp;
    }
}

// Round 5
// 639.600 us; speedup vs baseline: 1.9510x; 1.2451x over previous
//
#include <hip/hip_runtime.h>
#include <hip/hip_bf16.h>

#define NN 50000
#define NE 1600000

typedef __attribute__((ext_vector_type(8))) short bf16x8;
typedef __attribute__((ext_vector_type(4))) float f32x4;

// ---- workspace layout (byte offsets) ----
#define B_HAG   0                              // NN*64 f32 = 12,800,000
#define B_QW    (B_HAG + NN*64*4)              // 8 f32 (pad to 32B)
#define B_W1TN  (B_QW + 32)                    // 3*64*32 f32
#define B_W1B   (B_W1TN + 3*64*32*4)           // 3*8*64*8 bf16 (packed B-frags)
#define B_XB0   (B_W1B + 3*8*64*8*2)           // NN*16 bf16
#define B_XB1   (B_XB0 + NN*16*2)              // NN*16 bf16
#define B_PAB   (B_XB1 + NN*16*2)              // NE*4 bf16 (sorted pa)
#define B_SRC   (B_PAB + NE*4*2)               // NE int
#define B_DST   (B_SRC + NE*4)                 // NE int
#define B_DEG   (B_DST + NE*4)                 // NN int
#define B_CUR   (B_DEG + NN*4)                 // NN int
#define B_OFF   (B_CUR + NN*4)                 // NN+1 int
#define B_END   (B_OFF + (NN+1)*4)             // ~42.25 MB (proven ws >= 48.7MB in R4)

static __device__ __forceinline__ unsigned short f2bf(float f) {
    union { __hip_bfloat16 h; unsigned short u; } cv;
    cv.h = __float2bfloat16(f);
    return cv.u;
}
static __device__ __forceinline__ unsigned pk2(float a, float b) {
    unsigned r;
    asm("v_cvt_pk_bf16_f32 %0, %1, %2" : "=v"(r) : "v"(a), "v"(b));
    return r;
}
static __device__ __forceinline__ float bf2f(unsigned short u) {
    return __uint_as_float((unsigned)u << 16);
}

// ---------------------------------------------------------------------------
// prep: build packed MFMA B-operand w1b[l][frag=t*2+s][lane][e] covering the
// folded edge stage-1 weight matrix W1ext[K=64][N=64]:
//   k 0..15  = W1 rows for x_dst ; k 16..31 = W1 rows for x_src ;
//   k 32..35 = Mm (edge-embed fold) ; k 36 = c0 (bias via const-1 col) ; else 0.
// Also: node W1 transpose, q-collapse weights.
// ---------------------------------------------------------------------------
__global__ void prep_kernel(const float* __restrict__ ew1, const float* __restrict__ eb1,
                            const float* __restrict__ nw1,
                            const float* __restrict__ eeW, const float* __restrict__ eeB,
                            const float* __restrict__ few, const float* __restrict__ feb,
                            unsigned short* __restrict__ w1b, float* __restrict__ w1tn,
                            float* __restrict__ qw)
{
    int t0 = blockIdx.x * blockDim.x + threadIdx.x;
    int stride = gridDim.x * blockDim.x;
    for (int idx = t0; idx < 3 * 64 * 32; idx += stride) {
        int l = idx / 2048, r = idx % 2048, j = r / 32, i = r % 32;
        w1tn[idx] = nw1[l * 2048 + i * 64 + j];   // node_mlp_w1 [3][32][64] -> [3][64][32]
    }
    for (int idx = t0; idx < 3 * 8 * 64 * 8; idx += stride) {
        int l = idx >> 12;
        int r = idx & 4095;
        int f = r >> 9;               // frag 0..7 = t*2+s
        int lane = (r >> 3) & 63;
        int e = r & 7;
        int tt = f >> 1, s = f & 1;
        int k = ((lane >> 4) << 3) + e + (s << 5);
        int j = (tt << 4) + (lane & 15);
        float v = 0.f;
        if (k < 32) {
            v = ew1[l * 3072 + k * 64 + j];
        } else if (k < 36) {
            int f2 = k - 32;
            float acc = 0.f;
            for (int m = 0; m < 16; m++) acc += eeW[f2 * 16 + m] * ew1[l * 3072 + (32 + m) * 64 + j];
            v = acc;
        } else if (k == 36) {
            float acc = eb1[l * 64 + j];
            for (int m = 0; m < 16; m++) acc += eeB[m] * ew1[l * 3072 + (32 + m) * 64 + j];
            v = acc;
        }
        w1b[idx] = f2bf(v);
    }
    if (t0 < 4) {
        float s = 0.f;
        for (int k = 0; k < 16; k++) s += eeW[t0 * 16 + k] * few[k];
        qw[t0] = s;
    } else if (t0 == 4) {
        float s = feb[0];
        for (int k = 0; k < 16; k++) s += eeB[k] * few[k];
        qw[4] = s;
    }
}

// ---------------------------------------------------------------------------
// node init: xb0 = bf16(leak*w+b) ; zero deg, cursor, hag
// ---------------------------------------------------------------------------
__global__ __launch_bounds__(256) void node_init_kernel(
    const float* __restrict__ leak, const float* __restrict__ nw, const float* __restrict__ nb,
    unsigned short* __restrict__ xb0, float* __restrict__ hag,
    int* __restrict__ deg, int* __restrict__ cur)
{
    int n = blockIdx.x * blockDim.x + threadIdx.x;
    if (n >= NN) return;
    float la = leak[n];
    float v[16];
    #pragma unroll
    for (int i = 0; i < 16; i++) v[i] = la * nw[i] + nb[i];
    unsigned pk[8];
    #pragma unroll
    for (int i = 0; i < 8; i++) pk[i] = pk2(v[2 * i], v[2 * i + 1]);
    uint4* xo = reinterpret_cast<uint4*>(xb0 + n * 16);
    xo[0] = make_uint4(pk[0], pk[1], pk[2], pk[3]);
    xo[1] = make_uint4(pk[4], pk[5], pk[6], pk[7]);
    deg[n] = 0;
    cur[n] = 0;
    float4 z = {0.f, 0.f, 0.f, 0.f};
    float4* hp = reinterpret_cast<float4*>(hag + n * 64);
    #pragma unroll
    for (int j = 0; j < 16; j++) hp[j] = z;
}

// ---------------------------------------------------------------------------
// edge init: q output (collapsed linear) + int degree histogram
// ---------------------------------------------------------------------------
__global__ __launch_bounds__(256) void edge_init_kernel(
    const float* __restrict__ pa, const int* __restrict__ dst,
    const float* __restrict__ qw, float* __restrict__ qout, int* __restrict__ deg)
{
    int t = blockIdx.x * blockDim.x + threadIdx.x;
    if (t >= NE) return;
    float4 p = reinterpret_cast<const float4*>(pa)[t];
    qout[t] = qw[4] + p.x * qw[0] + p.y * qw[1] + p.z * qw[2] + p.w * qw[3];
    atomicAdd(&deg[dst[t]], 1);
}

// ---------------------------------------------------------------------------
// single-block exclusive scan of deg[NN] -> off[NN+1]
// ---------------------------------------------------------------------------
#define SCAN_T 1024
#define SCAN_C 49
__global__ __launch_bounds__(SCAN_T) void scan_kernel(const int* __restrict__ deg, int* __restrict__ off)
{
    __shared__ int part[SCAN_T];
    int tid = threadIdx.x;
    int base = tid * SCAN_C;
    int s = 0;
    for (int i = 0; i < SCAN_C; i++) {
        int idx = base + i;
        if (idx < NN) s += deg[idx];
    }
    part[tid] = s;
    __syncthreads();
    for (int o = 1; o < SCAN_T; o <<= 1) {
        int v = (tid >= o) ? part[tid - o] : 0;
        __syncthreads();
        part[tid] += v;
        __syncthreads();
    }
    int run = part[tid] - s;
    for (int i = 0; i < SCAN_C; i++) {
        int idx = base + i;
        if (idx < NN) { off[idx] = run; run += deg[idx]; }
    }
    if (tid == SCAN_T - 1) off[NN] = part[SCAN_T - 1];
}

// ---------------------------------------------------------------------------
// scatter into dst-sorted order: src_s, dst_s, pab (bf16 pa)
// ---------------------------------------------------------------------------
__global__ __launch_bounds__(256) void scatter_kernel(
    const int* __restrict__ ei, const float* __restrict__ pa,
    const int* __restrict__ off, int* __restrict__ cur,
    int* __restrict__ src_s, int* __restrict__ dst_s, unsigned short* __restrict__ pab)
{
    int t = blockIdx.x * blockDim.x + threadIdx.x;
    if (t >= NE) return;
    int d = ei[NE + t];
    int pos = off[d] + atomicAdd(&cur[d], 1);
    src_s[pos] = ei[t];
    dst_s[pos] = d;
    float4 p = reinterpret_cast<const float4*>(pa)[t];
    ushort4 pv;
    pv.x = f2bf(p.x); pv.y = f2bf(p.y); pv.z = f2bf(p.z); pv.w = f2bf(p.w);
    *reinterpret_cast<ushort4*>(pab + (size_t)pos * 4) = pv;
}

// ---------------------------------------------------------------------------
// MFMA edge kernel. Per wave: 64 dst-sorted edges = 4 tiles of 16 edges.
// A-frag (zero-LDS): lane l holds row l&15 (edge), k (l>>4)*8+e:
//   K-step 0 = [xd(16), xs(16)]  -> one dwordx4 from xb per lane
//   K-step 1 = [pa(4), 1, 0...]  -> pab dwordx2 for p==0 lanes, else 0
// 8 MFMAs vs W1ext B-frags (preloaded). C: col=lane&15 (j), row=(lane>>4)*4+reg
// (edge). relu -> bf16 -> LDS h[j=64][edge=64], then per-wave segmented
// column-sum -> coalesced 64-lane f32 atomics into hag[N][64].
// ---------------------------------------------------------------------------
__global__ __launch_bounds__(256) void edge_mfma_kernel(
    const unsigned short* __restrict__ xb,
    const int* __restrict__ src_s, const int* __restrict__ dst_s,
    const unsigned short* __restrict__ pab,
    const int* __restrict__ off,
    const unsigned short* __restrict__ w1b,   // this layer's 8 B-frags [8][64][8]
    float* __restrict__ hag)
{
    __shared__ unsigned short hbuf[4][64 * 68];
    int tid = threadIdx.x;
    int lane = tid & 63;
    int wid = tid >> 6;
    int wave = blockIdx.x * 4 + wid;
    int base = wave * 64;                  // NE % 64 == 0
    if (base >= NE) return;
    int ar = lane & 15;
    int ap = lane >> 4;
    unsigned short* hb = &hbuf[wid][0];

    // preload B fragments (8 x 16B)
    bf16x8 Bf[8];
    const bf16x8* w1v = reinterpret_cast<const bf16x8*>(w1b);
    #pragma unroll
    for (int i = 0; i < 8; i++) Bf[i] = w1v[i * 64 + lane];

    #pragma unroll 1
    for (int tile = 0; tile < 4; tile++) {
        int eb = base + tile * 16;
        int drow = dst_s[eb + ar];
        int srow = src_s[eb + ar];
        int xrow = (ap < 2) ? drow : srow;
        bf16x8 a0 = *reinterpret_cast<const bf16x8*>(xb + (size_t)xrow * 16 + (ap & 1) * 8);
        bf16x8 a1 = 0;
        if (ap == 0) {
            ushort4 pv = *reinterpret_cast<const ushort4*>(pab + (size_t)(eb + ar) * 4);
            a1[0] = (short)pv.x; a1[1] = (short)pv.y;
            a1[2] = (short)pv.z; a1[3] = (short)pv.w;
            a1[4] = (short)0x3f80;   // 1.0 bf16 -> bias column
        }
        f32x4 C0 = {0.f, 0.f, 0.f, 0.f}, C1 = C0, C2 = C0, C3 = C0;
        C0 = __builtin_amdgcn_mfma_f32_16x16x32_bf16(a0, Bf[0], C0, 0, 0, 0);
        C0 = __builtin_amdgcn_mfma_f32_16x16x32_bf16(a1, Bf[1], C0, 0, 0, 0);
        C1 = __builtin_amdgcn_mfma_f32_16x16x32_bf16(a0, Bf[2], C1, 0, 0, 0);
        C1 = __builtin_amdgcn_mfma_f32_16x16x32_bf16(a1, Bf[3], C1, 0, 0, 0);
        C2 = __builtin_amdgcn_mfma_f32_16x16x32_bf16(a0, Bf[4], C2, 0, 0, 0);
        C2 = __builtin_amdgcn_mfma_f32_16x16x32_bf16(a1, Bf[5], C2, 0, 0, 0);
        C3 = __builtin_amdgcn_mfma_f32_16x16x32_bf16(a0, Bf[6], C3, 0, 0, 0);
        C3 = __builtin_amdgcn_mfma_f32_16x16x32_bf16(a1, Bf[7], C3, 0, 0, 0);

        // epilogue: relu + pack pairs of edges, store h[j][edge] (bf16)
        int eoff = tile * 16 + ap * 4;
        {
            unsigned lo = pk2(fmaxf(C0[0], 0.f), fmaxf(C0[1], 0.f));
            unsigned hi = pk2(fmaxf(C0[2], 0.f), fmaxf(C0[3], 0.f));
            *reinterpret_cast<uint2*>(hb + (0 * 16 + ar) * 68 + eoff) = make_uint2(lo, hi);
        }
        {
            unsigned lo = pk2(fmaxf(C1[0], 0.f), fmaxf(C1[1], 0.f));
            unsigned hi = pk2(fmaxf(C1[2], 0.f), fmaxf(C1[3], 0.f));
            *reinterpret_cast<uint2*>(hb + (1 * 16 + ar) * 68 + eoff) = make_uint2(lo, hi);
        }
        {
            unsigned lo = pk2(fmaxf(C2[0], 0.f), fmaxf(C2[1], 0.f));
            unsigned hi = pk2(fmaxf(C2[2], 0.f), fmaxf(C2[3], 0.f));
            *reinterpret_cast<uint2*>(hb + (2 * 16 + ar) * 68 + eoff) = make_uint2(lo, hi);
        }
        {
            unsigned lo = pk2(fmaxf(C3[0], 0.f), fmaxf(C3[1], 0.f));
            unsigned hi = pk2(fmaxf(C3[2], 0.f), fmaxf(C3[3], 0.f));
            *reinterpret_cast<uint2*>(hb + (3 * 16 + ar) * 68 + eoff) = make_uint2(lo, hi);
        }
    }

    asm volatile("s_waitcnt lgkmcnt(0)" ::: "memory");
    __builtin_amdgcn_sched_barrier(0);

    // segmented column-sum: lane owns hidden unit j = lane
    int lo = 0, hi = NN;
    while (hi - lo > 1) {
        int mid = (lo + hi) >> 1;
        if (off[mid] <= base) lo = mid; else hi = mid;
    }
    int d = lo;
    int e = base;
    const int lim = base + 64;
    const unsigned short* hr = hb + lane * 68;
    while (e < lim) {
        int segend = off[d + 1];
        int eend = segend < lim ? segend : lim;
        float acc = 0.f;
        for (int i = e; i < eend; ++i) acc += bf2f(hr[i - base]);
        unsafeAtomicAdd(&hag[(size_t)d * 64 + lane], acc);
        e = eend;
        if (segend <= lim) ++d;
    }
}

// ---------------------------------------------------------------------------
// node update: aggr = W2^T(hag)/deg + b2 (0 if deg==0), then 32->64->16 MLP.
// Reads/writes bf16 x-tables. Re-zeros hag. Emits H on last layer.
// ---------------------------------------------------------------------------
__global__ __launch_bounds__(256) void node_mlp_kernel(
    const unsigned short* __restrict__ xb, unsigned short* __restrict__ xbn,
    float* __restrict__ hag, const int* __restrict__ off,
    const float* __restrict__ ew2, const float* __restrict__ eb2,
    const float* __restrict__ nw1t, const float* __restrict__ nb1,
    const float* __restrict__ nw2, const float* __restrict__ nb2,
    const float* __restrict__ fnw, const float* __restrict__ fnb,
    float* __restrict__ Hout, int writeH)
{
    int n = blockIdx.x * blockDim.x + threadIdx.x;
    if (n >= NN) return;
    float u[32];
    const uint4* xp = reinterpret_cast<const uint4*>(xb + n * 16);
    uint4 xa = xp[0], xbv = xp[1];
    {
        unsigned w[8] = {xa.x, xa.y, xa.z, xa.w, xbv.x, xbv.y, xbv.z, xbv.w};
        #pragma unroll
        for (int i = 0; i < 8; i++) {
            u[2 * i]     = __uint_as_float(w[i] << 16);
            u[2 * i + 1] = __uint_as_float(w[i] & 0xffff0000u);
        }
    }
    int dg = off[n + 1] - off[n];
    float inv = 1.0f / (float)(dg > 0 ? dg : 1);
    float bsc = (dg > 0) ? 1.0f : 0.0f;
    float tacc[16];
    #pragma unroll
    for (int k = 0; k < 16; k++) tacc[k] = 0.f;
    float4* hp4 = reinterpret_cast<float4*>(hag + (size_t)n * 64);
    #pragma unroll 1
    for (int j4 = 0; j4 < 16; j4++) {
        float4 hv = hp4[j4];
        int j = j4 * 4;
        #pragma unroll
        for (int k = 0; k < 16; k++) {
            tacc[k] += hv.x * ew2[(j + 0) * 16 + k];
            tacc[k] += hv.y * ew2[(j + 1) * 16 + k];
            tacc[k] += hv.z * ew2[(j + 2) * 16 + k];
            tacc[k] += hv.w * ew2[(j + 3) * 16 + k];
        }
    }
    float4 z = {0.f, 0.f, 0.f, 0.f};
    #pragma unroll
    for (int j4 = 0; j4 < 16; j4++) hp4[j4] = z;   // re-zero for next layer
    #pragma unroll
    for (int k = 0; k < 16; k++) u[16 + k] = bsc * eb2[k] + tacc[k] * inv;

    float o[16];
    #pragma unroll
    for (int k = 0; k < 16; k++) o[k] = nb2[k];
    #pragma unroll 1
    for (int j = 0; j < 64; j++) {
        float h = nb1[j];
        const float* wr = nw1t + j * 32;
        #pragma unroll
        for (int i = 0; i < 32; i++) h += u[i] * wr[i];
        h = fmaxf(h, 0.f);
        #pragma unroll
        for (int k = 0; k < 16; k++) o[k] += h * nw2[j * 16 + k];
    }
    unsigned pk[8];
    #pragma unroll
    for (int i = 0; i < 8; i++) pk[i] = pk2(o[2 * i], o[2 * i + 1]);
    uint4* xo = reinterpret_cast<uint4*>(xbn + n * 16);
    xo[0] = make_uint4(pk[0], pk[1], pk[2], pk[3]);
    xo[1] = make_uint4(pk[4], pk[5], pk[6], pk[7]);
    if (writeH) {
        float s = fnb[0];
        #pragma unroll
        for (int k = 0; k < 16; k++) s += o[k] * fnw[k];
        Hout[n] = s;
    }
}

extern "C" void kernel_launch(void* const* d_in, const int* in_sizes, int n_in,
                              void* d_out, int out_size, void* d_ws, size_t ws_size,
                              hipStream_t stream)
{
    const float* leak = (const float*)d_in[0];
    const float* pa   = (const float*)d_in[1];
    const int*   ei   = (const int*)d_in[2];
    const float* neww = (const float*)d_in[3];
    const float* newb = (const float*)d_in[4];
    const float* eeW  = (const float*)d_in[5];
    const float* eeB  = (const float*)d_in[6];
    const float* ew1  = (const float*)d_in[7];
    const float* eb1  = (const float*)d_in[8];
    const float* ew2  = (const float*)d_in[9];
    const float* eb2  = (const float*)d_in[10];
    const float* nw1  = (const float*)d_in[11];
    const float* nb1  = (const float*)d_in[12];
    const float* nw2  = (const float*)d_in[13];
    const float* nb2  = (const float*)d_in[14];
    const float* fnw  = (const float*)d_in[15];
    const float* fnb  = (const float*)d_in[16];
    const float* few  = (const float*)d_in[17];
    const float* feb  = (const float*)d_in[18];

    char* wsb = (char*)d_ws;
    float*          hag  = (float*)(wsb + B_HAG);
    float*          qw   = (float*)(wsb + B_QW);
    float*          w1tn = (float*)(wsb + B_W1TN);
    unsigned short* w1b  = (unsigned short*)(wsb + B_W1B);
    unsigned short* xb0  = (unsigned short*)(wsb + B_XB0);
    unsigned short* xb1  = (unsigned short*)(wsb + B_XB1);
    unsigned short* pab  = (unsigned short*)(wsb + B_PAB);
    int*            srcs = (int*)(wsb + B_SRC);
    int*            dsts = (int*)(wsb + B_DST);
    int*            deg  = (int*)(wsb + B_DEG);
    int*            cur  = (int*)(wsb + B_CUR);
    int*            off  = (int*)(wsb + B_OFF);

    float* H = (float*)d_out;
    float* q = (float*)d_out + NN;
    const int* dstp = ei + NE;

    prep_kernel<<<16, 256, 0, stream>>>(ew1, eb1, nw1, eeW, eeB, few, feb,
                                        w1b, w1tn, qw);
    node_init_kernel<<<(NN + 255) / 256, 256, 0, stream>>>(leak, neww, newb, xb0, hag, deg, cur);
    edge_init_kernel<<<(NE + 255) / 256, 256, 0, stream>>>(pa, dstp, qw, q, deg);
    scan_kernel<<<1, SCAN_T, 0, stream>>>(deg, off);
    scatter_kernel<<<(NE + 255) / 256, 256, 0, stream>>>(ei, pa, off, cur, srcs, dsts, pab);

    unsigned short* xcur = xb0;
    unsigned short* xnxt = xb1;
    for (int l = 0; l < 3; l++) {
        edge_mfma_kernel<<<NE / 256, 256, 0, stream>>>(
            xcur, srcs, dsts, pab, off, w1b + l * 4096, hag);
        node_mlp_kernel<<<(NN + 255) / 256, 256, 0, stream>>>(
            xcur, xnxt, hag, off, ew2 + l * 1024, eb2 + l * 16,
            w1tn + l * 2048, nb1 + l * 64, nw2 + l * 1024, nb2 + l * 16,
            fnw, fnb, H, (l == 2) ? 1 : 0);
        unsigned short* tmp = xcur; xcur = xnxt; xnxt = tmp;
    }
}

// Round 6
// 634.329 us; speedup vs baseline: 1.9672x; 1.0083x over previous
//
#include <hip/hip_runtime.h>
#include <hip/hip_bf16.h>

#define NN 50000
#define NE 1600000

typedef __attribute__((ext_vector_type(8))) short bf16x8;
typedef __attribute__((ext_vector_type(4))) float f32x4;

// ---- workspace layout (byte offsets) ----
#define B_HAG   0                              // NN*64 f32 = 12,800,000
#define B_QW    (B_HAG + NN*64*4)              // 8 f32 (pad to 32B)
#define B_W1TN  (B_QW + 32)                    // 3*64*32 f32
#define B_W1B   (B_W1TN + 3*64*32*4)           // 3*8*64*8 bf16 (packed B-frags)
#define B_XB0   (B_W1B + 3*8*64*8*2)           // NN*16 bf16
#define B_XB1   (B_XB0 + NN*16*2)              // NN*16 bf16
#define B_EPK   (B_XB1 + NN*16*2)              // NE uint4 packed {src,dst,pa01,pa23}
#define B_DEG   (B_EPK + NE*16)                // NN int
#define B_CUR   (B_DEG + NN*4)                 // NN int
#define B_OFF   (B_CUR + NN*4)                 // NN+1 int
#define B_END   (B_OFF + (NN+1)*4)             // ~42.25 MB (same footprint as R5)

static __device__ __forceinline__ unsigned short f2bf(float f) {
    union { __hip_bfloat16 h; unsigned short u; } cv;
    cv.h = __float2bfloat16(f);
    return cv.u;
}
static __device__ __forceinline__ unsigned pk2(float a, float b) {
    unsigned r;
    asm("v_cvt_pk_bf16_f32 %0, %1, %2" : "=v"(r) : "v"(a), "v"(b));
    return r;
}
static __device__ __forceinline__ float bf2f(unsigned short u) {
    return __uint_as_float((unsigned)u << 16);
}

// ---------------------------------------------------------------------------
// prep: build packed MFMA B-operand w1b[l][frag=t*2+s][lane][e] covering the
// folded edge stage-1 weight matrix W1ext[K=64][N=64]:
//   k 0..15  = W1 rows for x_dst ; k 16..31 = W1 rows for x_src ;
//   k 32..35 = Mm (edge-embed fold) ; k 36 = c0 (bias via const-1 col) ; else 0.
// Also: node W1 transpose, q-collapse weights.
// ---------------------------------------------------------------------------
__global__ void prep_kernel(const float* __restrict__ ew1, const float* __restrict__ eb1,
                            const float* __restrict__ nw1,
                            const float* __restrict__ eeW, const float* __restrict__ eeB,
                            const float* __restrict__ few, const float* __restrict__ feb,
                            unsigned short* __restrict__ w1b, float* __restrict__ w1tn,
                            float* __restrict__ qw)
{
    int t0 = blockIdx.x * blockDim.x + threadIdx.x;
    int stride = gridDim.x * blockDim.x;
    for (int idx = t0; idx < 3 * 64 * 32; idx += stride) {
        int l = idx / 2048, r = idx % 2048, j = r / 32, i = r % 32;
        w1tn[idx] = nw1[l * 2048 + i * 64 + j];   // node_mlp_w1 [3][32][64] -> [3][64][32]
    }
    for (int idx = t0; idx < 3 * 8 * 64 * 8; idx += stride) {
        int l = idx >> 12;
        int r = idx & 4095;
        int f = r >> 9;               // frag 0..7 = t*2+s
        int lane = (r >> 3) & 63;
        int e = r & 7;
        int tt = f >> 1, s = f & 1;
        int k = ((lane >> 4) << 3) + e + (s << 5);
        int j = (tt << 4) + (lane & 15);
        float v = 0.f;
        if (k < 32) {
            v = ew1[l * 3072 + k * 64 + j];
        } else if (k < 36) {
            int f2 = k - 32;
            float acc = 0.f;
            for (int m = 0; m < 16; m++) acc += eeW[f2 * 16 + m] * ew1[l * 3072 + (32 + m) * 64 + j];
            v = acc;
        } else if (k == 36) {
            float acc = eb1[l * 64 + j];
            for (int m = 0; m < 16; m++) acc += eeB[m] * ew1[l * 3072 + (32 + m) * 64 + j];
            v = acc;
        }
        w1b[idx] = f2bf(v);
    }
    if (t0 < 4) {
        float s = 0.f;
        for (int k = 0; k < 16; k++) s += eeW[t0 * 16 + k] * few[k];
        qw[t0] = s;
    } else if (t0 == 4) {
        float s = feb[0];
        for (int k = 0; k < 16; k++) s += eeB[k] * few[k];
        qw[4] = s;
    }
}

// ---------------------------------------------------------------------------
// node init: xb0 = bf16(leak*w+b) ; zero deg, cursor, hag
// ---------------------------------------------------------------------------
__global__ __launch_bounds__(256) void node_init_kernel(
    const float* __restrict__ leak, const float* __restrict__ nw, const float* __restrict__ nb,
    unsigned short* __restrict__ xb0, float* __restrict__ hag,
    int* __restrict__ deg, int* __restrict__ cur)
{
    int n = blockIdx.x * blockDim.x + threadIdx.x;
    if (n >= NN) return;
    float la = leak[n];
    float v[16];
    #pragma unroll
    for (int i = 0; i < 16; i++) v[i] = la * nw[i] + nb[i];
    unsigned pk[8];
    #pragma unroll
    for (int i = 0; i < 8; i++) pk[i] = pk2(v[2 * i], v[2 * i + 1]);
    uint4* xo = reinterpret_cast<uint4*>(xb0 + n * 16);
    xo[0] = make_uint4(pk[0], pk[1], pk[2], pk[3]);
    xo[1] = make_uint4(pk[4], pk[5], pk[6], pk[7]);
    deg[n] = 0;
    cur[n] = 0;
    float4 z = {0.f, 0.f, 0.f, 0.f};
    float4* hp = reinterpret_cast<float4*>(hag + n * 64);
    #pragma unroll
    for (int j = 0; j < 16; j++) hp[j] = z;
}

// ---------------------------------------------------------------------------
// edge init: int degree histogram only (q moved to scatter)
// ---------------------------------------------------------------------------
__global__ __launch_bounds__(256) void edge_init_kernel(
    const int* __restrict__ dst, int* __restrict__ deg)
{
    int t = blockIdx.x * blockDim.x + threadIdx.x;
    if (t >= NE) return;
    atomicAdd(&deg[dst[t]], 1);
}

// ---------------------------------------------------------------------------
// single-block exclusive scan of deg[NN] -> off[NN+1]
// ---------------------------------------------------------------------------
#define SCAN_T 1024
#define SCAN_C 49
__global__ __launch_bounds__(SCAN_T) void scan_kernel(const int* __restrict__ deg, int* __restrict__ off)
{
    __shared__ int part[SCAN_T];
    int tid = threadIdx.x;
    int base = tid * SCAN_C;
    int s = 0;
    for (int i = 0; i < SCAN_C; i++) {
        int idx = base + i;
        if (idx < NN) s += deg[idx];
    }
    part[tid] = s;
    __syncthreads();
    for (int o = 1; o < SCAN_T; o <<= 1) {
        int v = (tid >= o) ? part[tid - o] : 0;
        __syncthreads();
        part[tid] += v;
        __syncthreads();
    }
    int run = part[tid] - s;
    for (int i = 0; i < SCAN_C; i++) {
        int idx = base + i;
        if (idx < NN) { off[idx] = run; run += deg[idx]; }
    }
    if (tid == SCAN_T - 1) off[NN] = part[SCAN_T - 1];
}

// ---------------------------------------------------------------------------
// scatter into dst-sorted order: single packed uint4 {src, dst, pa01, pa23}
// per edge (one random cache line instead of three). Also emits q output.
// ---------------------------------------------------------------------------
__global__ __launch_bounds__(256) void scatter_kernel(
    const int* __restrict__ ei, const float* __restrict__ pa,
    const int* __restrict__ off, int* __restrict__ cur,
    const float* __restrict__ qw, float* __restrict__ qout,
    uint4* __restrict__ epk)
{
    int t = blockIdx.x * blockDim.x + threadIdx.x;
    if (t >= NE) return;
    float4 p = reinterpret_cast<const float4*>(pa)[t];
    qout[t] = qw[4] + p.x * qw[0] + p.y * qw[1] + p.z * qw[2] + p.w * qw[3];
    int d = ei[NE + t];
    int pos = off[d] + atomicAdd(&cur[d], 1);
    uint4 v;
    v.x = (unsigned)ei[t];
    v.y = (unsigned)d;
    v.z = pk2(p.x, p.y);
    v.w = pk2(p.z, p.w);
    epk[pos] = v;
}

// ---------------------------------------------------------------------------
// MFMA edge kernel. Per wave: 64 dst-sorted edges = 4 tiles of 16 edges.
// A-frag (zero-LDS): lane l holds row l&15 (edge), k (l>>4)*8+e:
//   K-step 0 = [xd(16), xs(16)]  -> one dwordx4 from xb per lane
//   K-step 1 = [pa(4), 1, 0...]  -> from the packed epk record (ap==0 lanes)
// 8 MFMAs vs W1ext B-frags (preloaded). C: col=lane&15 (j), row=(lane>>4)*4+reg
// (edge). relu -> bf16 -> LDS h[j=64][edge=64], then per-wave segmented
// column-sum (uint2 = 4 bf16 per LDS read) -> coalesced f32 atomics into hag.
// ---------------------------------------------------------------------------
__global__ __launch_bounds__(256) void edge_mfma_kernel(
    const unsigned short* __restrict__ xb,
    const uint4* __restrict__ epk,
    const int* __restrict__ off,
    const unsigned short* __restrict__ w1b,   // this layer's 8 B-frags [8][64][8]
    float* __restrict__ hag)
{
    __shared__ unsigned short hbuf[4][64 * 68];
    int tid = threadIdx.x;
    int lane = tid & 63;
    int wid = tid >> 6;
    int wave = blockIdx.x * 4 + wid;
    int base = wave * 64;                  // NE % 64 == 0
    if (base >= NE) return;
    int ar = lane & 15;
    int ap = lane >> 4;
    unsigned short* hb = &hbuf[wid][0];

    // binary search first (overlaps with B-frag loads / MFMA latency):
    // largest d0 with off[d0] <= base
    int lo = 0, hi = NN;
    while (hi - lo > 1) {
        int mid = (lo + hi) >> 1;
        if (off[mid] <= base) lo = mid; else hi = mid;
    }
    int d0 = lo;

    // preload B fragments (8 x 16B)
    bf16x8 Bf[8];
    const bf16x8* w1v = reinterpret_cast<const bf16x8*>(w1b);
    #pragma unroll
    for (int i = 0; i < 8; i++) Bf[i] = w1v[i * 64 + lane];

    #pragma unroll 1
    for (int tile = 0; tile < 4; tile++) {
        int eb = base + tile * 16;
        uint4 ev = epk[eb + ar];
        int xrow = (ap < 2) ? (int)ev.y : (int)ev.x;
        bf16x8 a0 = *reinterpret_cast<const bf16x8*>(xb + (size_t)xrow * 16 + (ap & 1) * 8);
        bf16x8 a1 = 0;
        if (ap == 0) {
            a1[0] = (short)(ev.z & 0xffffu);
            a1[1] = (short)(ev.z >> 16);
            a1[2] = (short)(ev.w & 0xffffu);
            a1[3] = (short)(ev.w >> 16);
            a1[4] = (short)0x3f80;   // 1.0 bf16 -> bias column
        }
        f32x4 C0 = {0.f, 0.f, 0.f, 0.f}, C1 = C0, C2 = C0, C3 = C0;
        C0 = __builtin_amdgcn_mfma_f32_16x16x32_bf16(a0, Bf[0], C0, 0, 0, 0);
        C0 = __builtin_amdgcn_mfma_f32_16x16x32_bf16(a1, Bf[1], C0, 0, 0, 0);
        C1 = __builtin_amdgcn_mfma_f32_16x16x32_bf16(a0, Bf[2], C1, 0, 0, 0);
        C1 = __builtin_amdgcn_mfma_f32_16x16x32_bf16(a1, Bf[3], C1, 0, 0, 0);
        C2 = __builtin_amdgcn_mfma_f32_16x16x32_bf16(a0, Bf[4], C2, 0, 0, 0);
        C2 = __builtin_amdgcn_mfma_f32_16x16x32_bf16(a1, Bf[5], C2, 0, 0, 0);
        C3 = __builtin_amdgcn_mfma_f32_16x16x32_bf16(a0, Bf[6], C3, 0, 0, 0);
        C3 = __builtin_amdgcn_mfma_f32_16x16x32_bf16(a1, Bf[7], C3, 0, 0, 0);

        // epilogue: relu + pack pairs of edges, store h[j][edge] (bf16)
        int eoff = tile * 16 + ap * 4;
        {
            unsigned lov = pk2(fmaxf(C0[0], 0.f), fmaxf(C0[1], 0.f));
            unsigned hiv = pk2(fmaxf(C0[2], 0.f), fmaxf(C0[3], 0.f));
            *reinterpret_cast<uint2*>(hb + (0 * 16 + ar) * 68 + eoff) = make_uint2(lov, hiv);
        }
        {
            unsigned lov = pk2(fmaxf(C1[0], 0.f), fmaxf(C1[1], 0.f));
            unsigned hiv = pk2(fmaxf(C1[2], 0.f), fmaxf(C1[3], 0.f));
            *reinterpret_cast<uint2*>(hb + (1 * 16 + ar) * 68 + eoff) = make_uint2(lov, hiv);
        }
        {
            unsigned lov = pk2(fmaxf(C2[0], 0.f), fmaxf(C2[1], 0.f));
            unsigned hiv = pk2(fmaxf(C2[2], 0.f), fmaxf(C2[3], 0.f));
            *reinterpret_cast<uint2*>(hb + (2 * 16 + ar) * 68 + eoff) = make_uint2(lov, hiv);
        }
        {
            unsigned lov = pk2(fmaxf(C3[0], 0.f), fmaxf(C3[1], 0.f));
            unsigned hiv = pk2(fmaxf(C3[2], 0.f), fmaxf(C3[3], 0.f));
            *reinterpret_cast<uint2*>(hb + (3 * 16 + ar) * 68 + eoff) = make_uint2(lov, hiv);
        }
    }

    asm volatile("s_waitcnt lgkmcnt(0)" ::: "memory");
    __builtin_amdgcn_sched_barrier(0);

    // segmented column-sum: lane owns hidden unit j = lane.
    // Packed uint2 (4 bf16) LDS reads with scalar head/tail at boundaries.
    int d = d0;
    int e = base;
    const int lim = base + 64;
    const unsigned short* hr = hb + lane * 68;
    while (e < lim) {
        int segend = off[d + 1];
        int eend = segend < lim ? segend : lim;
        float acc = 0.f;
        int i = e - base, iend = eend - base;
        for (; (i & 3) != 0 && i < iend; ++i) acc += bf2f(hr[i]);
        for (; i + 4 <= iend; i += 4) {
            uint2 u = *reinterpret_cast<const uint2*>(hr + i);
            acc += __uint_as_float(u.x << 16) + __uint_as_float(u.x & 0xffff0000u)
                 + __uint_as_float(u.y << 16) + __uint_as_float(u.y & 0xffff0000u);
        }
        for (; i < iend; ++i) acc += bf2f(hr[i]);
        unsafeAtomicAdd(&hag[(size_t)d * 64 + lane], acc);
        e = eend;
        if (segend <= lim) ++d;
    }
}

// ---------------------------------------------------------------------------
// node update: aggr = W2^T(hag)/deg + b2 (0 if deg==0), then 32->64->16 MLP.
// Reads/writes bf16 x-tables. Re-zeros hag. Emits H on last layer.
// ---------------------------------------------------------------------------
__global__ __launch_bounds__(256) void node_mlp_kernel(
    const unsigned short* __restrict__ xb, unsigned short* __restrict__ xbn,
    float* __restrict__ hag, const int* __restrict__ off,
    const float* __restrict__ ew2, const float* __restrict__ eb2,
    const float* __restrict__ nw1t, const float* __restrict__ nb1,
    const float* __restrict__ nw2, const float* __restrict__ nb2,
    const float* __restrict__ fnw, const float* __restrict__ fnb,
    float* __restrict__ Hout, int writeH)
{
    int n = blockIdx.x * blockDim.x + threadIdx.x;
    if (n >= NN) return;
    float u[32];
    const uint4* xp = reinterpret_cast<const uint4*>(xb + n * 16);
    uint4 xa = xp[0], xbv = xp[1];
    {
        unsigned w[8] = {xa.x, xa.y, xa.z, xa.w, xbv.x, xbv.y, xbv.z, xbv.w};
        #pragma unroll
        for (int i = 0; i < 8; i++) {
            u[2 * i]     = __uint_as_float(w[i] << 16);
            u[2 * i + 1] = __uint_as_float(w[i] & 0xffff0000u);
        }
    }
    int dg = off[n + 1] - off[n];
    float inv = 1.0f / (float)(dg > 0 ? dg : 1);
    float bsc = (dg > 0) ? 1.0f : 0.0f;
    float tacc[16];
    #pragma unroll
    for (int k = 0; k < 16; k++) tacc[k] = 0.f;
    float4* hp4 = reinterpret_cast<float4*>(hag + (size_t)n * 64);
    #pragma unroll 1
    for (int j4 = 0; j4 < 16; j4++) {
        float4 hv = hp4[j4];
        int j = j4 * 4;
        #pragma unroll
        for (int k = 0; k < 16; k++) {
            tacc[k] += hv.x * ew2[(j + 0) * 16 + k];
            tacc[k] += hv.y * ew2[(j + 1) * 16 + k];
            tacc[k] += hv.z * ew2[(j + 2) * 16 + k];
            tacc[k] += hv.w * ew2[(j + 3) * 16 + k];
        }
    }
    float4 z = {0.f, 0.f, 0.f, 0.f};
    #pragma unroll
    for (int j4 = 0; j4 < 16; j4++) hp4[j4] = z;   // re-zero for next layer
    #pragma unroll
    for (int k = 0; k < 16; k++) u[16 + k] = bsc * eb2[k] + tacc[k] * inv;

    float o[16];
    #pragma unroll
    for (int k = 0; k < 16; k++) o[k] = nb2[k];
    #pragma unroll 1
    for (int j = 0; j < 64; j++) {
        float h = nb1[j];
        const float* wr = nw1t + j * 32;
        #pragma unroll
        for (int i = 0; i < 32; i++) h += u[i] * wr[i];
        h = fmaxf(h, 0.f);
        #pragma unroll
        for (int k = 0; k < 16; k++) o[k] += h * nw2[j * 16 + k];
    }
    unsigned pk[8];
    #pragma unroll
    for (int i = 0; i < 8; i++) pk[i] = pk2(o[2 * i], o[2 * i + 1]);
    uint4* xo = reinterpret_cast<uint4*>(xbn + n * 16);
    xo[0] = make_uint4(pk[0], pk[1], pk[2], pk[3]);
    xo[1] = make_uint4(pk[4], pk[5], pk[6], pk[7]);
    if (writeH) {
        float s = fnb[0];
        #pragma unroll
        for (int k = 0; k < 16; k++) s += o[k] * fnw[k];
        Hout[n] = s;
    }
}

extern "C" void kernel_launch(void* const* d_in, const int* in_sizes, int n_in,
                              void* d_out, int out_size, void* d_ws, size_t ws_size,
                              hipStream_t stream)
{
    const float* leak = (const float*)d_in[0];
    const float* pa   = (const float*)d_in[1];
    const int*   ei   = (const int*)d_in[2];
    const float* neww = (const float*)d_in[3];
    const float* newb = (const float*)d_in[4];
    const float* eeW  = (const float*)d_in[5];
    const float* eeB  = (const float*)d_in[6];
    const float* ew1  = (const float*)d_in[7];
    const float* eb1  = (const float*)d_in[8];
    const float* ew2  = (const float*)d_in[9];
    const float* eb2  = (const float*)d_in[10];
    const float* nw1  = (const float*)d_in[11];
    const float* nb1  = (const float*)d_in[12];
    const float* nw2  = (const float*)d_in[13];
    const float* nb2  = (const float*)d_in[14];
    const float* fnw  = (const float*)d_in[15];
    const float* fnb  = (const float*)d_in[16];
    const float* few  = (const float*)d_in[17];
    const float* feb  = (const float*)d_in[18];

    char* wsb = (char*)d_ws;
    float*          hag  = (float*)(wsb + B_HAG);
    float*          qw   = (float*)(wsb + B_QW);
    float*          w1tn = (float*)(wsb + B_W1TN);
    unsigned short* w1b  = (unsigned short*)(wsb + B_W1B);
    unsigned short* xb0  = (unsigned short*)(wsb + B_XB0);
    unsigned short* xb1  = (unsigned short*)(wsb + B_XB1);
    uint4*          epk  = (uint4*)(wsb + B_EPK);
    int*            deg  = (int*)(wsb + B_DEG);
    int*            cur  = (int*)(wsb + B_CUR);
    int*            off  = (int*)(wsb + B_OFF);

    float* H = (float*)d_out;
    float* q = (float*)d_out + NN;
    const int* dstp = ei + NE;

    prep_kernel<<<16, 256, 0, stream>>>(ew1, eb1, nw1, eeW, eeB, few, feb,
                                        w1b, w1tn, qw);
    node_init_kernel<<<(NN + 255) / 256, 256, 0, stream>>>(leak, neww, newb, xb0, hag, deg, cur);
    edge_init_kernel<<<(NE + 255) / 256, 256, 0, stream>>>(dstp, deg);
    scan_kernel<<<1, SCAN_T, 0, stream>>>(deg, off);
    scatter_kernel<<<(NE + 255) / 256, 256, 0, stream>>>(ei, pa, off, cur, qw, q, epk);

    unsigned short* xcur = xb0;
    unsigned short* xnxt = xb1;
    for (int l = 0; l < 3; l++) {
        edge_mfma_kernel<<<NE / 256, 256, 0, stream>>>(
            xcur, epk, off, w1b + l * 4096, hag);
        node_mlp_kernel<<<(NN + 255) / 256, 256, 0, stream>>>(
            xcur, xnxt, hag, off, ew2 + l * 1024, eb2 + l * 16,
            w1tn + l * 2048, nb1 + l * 64, nw2 + l * 1024, nb2 + l * 16,
            fnw, fnb, H, (l == 2) ? 1 : 0);
        unsigned short* tmp = xcur; xcur = xnxt; xnxt = tmp;
    }
}

// Round 7
// 468.777 us; speedup vs baseline: 2.6619x; 1.3532x over previous
//
#include <hip/hip_runtime.h>
#include <hip/hip_bf16.h>

#define NN 50000
#define NE 1600000

typedef __attribute__((ext_vector_type(8))) short bf16x8;
typedef __attribute__((ext_vector_type(4))) float f32x4;

// ---- workspace layout (byte offsets) ----
#define B_HAG   0                              // NN*64 f32 = 12,800,000
#define B_QW    (B_HAG + NN*64*4)              // 8 f32 (pad to 32B)
#define B_W1TN  (B_QW + 32)                    // 3*64*32 f32
#define B_W1B   (B_W1TN + 3*64*32*4)           // 3*8*64*8 bf16 (packed B-frags)
#define B_XB0   (B_W1B + 3*8*64*8*2)           // NN*16 bf16
#define B_XB1   (B_XB0 + NN*16*2)              // NN*16 bf16
#define B_EPK   (B_XB1 + NN*16*2)              // NE uint4 packed {src,dst,pa01,pa23}
#define B_DEG   (B_EPK + NE*16)                // NN int
#define B_RNK   (B_DEG + NN*4)                 // NE int (sort rank per edge)
#define B_OFF   (B_RNK + NE*4)                 // NN+1 int
#define B_END   (B_OFF + (NN+1)*4)             // ~48.3 MB (ws >= 58.4MB proven in R4)

static __device__ __forceinline__ unsigned short f2bf(float f) {
    union { __hip_bfloat16 h; unsigned short u; } cv;
    cv.h = __float2bfloat16(f);
    return cv.u;
}
static __device__ __forceinline__ unsigned pk2(float a, float b) {
    unsigned r;
    asm("v_cvt_pk_bf16_f32 %0, %1, %2" : "=v"(r) : "v"(a), "v"(b));
    return r;
}
static __device__ __forceinline__ float bf2f(unsigned short u) {
    return __uint_as_float((unsigned)u << 16);
}

// ---------------------------------------------------------------------------
// prep: build packed MFMA B-operand w1b[l][frag=t*2+s][lane][e] covering the
// folded edge stage-1 weight matrix W1ext[K=64][N=64]:
//   k 0..15  = W1 rows for x_dst ; k 16..31 = W1 rows for x_src ;
//   k 32..35 = Mm (edge-embed fold) ; k 36 = c0 (bias via const-1 col) ; else 0.
// Also: node W1 transpose, q-collapse weights.
// ---------------------------------------------------------------------------
__global__ void prep_kernel(const float* __restrict__ ew1, const float* __restrict__ eb1,
                            const float* __restrict__ nw1,
                            const float* __restrict__ eeW, const float* __restrict__ eeB,
                            const float* __restrict__ few, const float* __restrict__ feb,
                            unsigned short* __restrict__ w1b, float* __restrict__ w1tn,
                            float* __restrict__ qw)
{
    int t0 = blockIdx.x * blockDim.x + threadIdx.x;
    int stride = gridDim.x * blockDim.x;
    for (int idx = t0; idx < 3 * 64 * 32; idx += stride) {
        int l = idx / 2048, r = idx % 2048, j = r / 32, i = r % 32;
        w1tn[idx] = nw1[l * 2048 + i * 64 + j];   // node_mlp_w1 [3][32][64] -> [3][64][32]
    }
    for (int idx = t0; idx < 3 * 8 * 64 * 8; idx += stride) {
        int l = idx >> 12;
        int r = idx & 4095;
        int f = r >> 9;               // frag 0..7 = t*2+s
        int lane = (r >> 3) & 63;
        int e = r & 7;
        int tt = f >> 1, s = f & 1;
        int k = ((lane >> 4) << 3) + e + (s << 5);
        int j = (tt << 4) + (lane & 15);
        float v = 0.f;
        if (k < 32) {
            v = ew1[l * 3072 + k * 64 + j];
        } else if (k < 36) {
            int f2 = k - 32;
            float acc = 0.f;
            for (int m = 0; m < 16; m++) acc += eeW[f2 * 16 + m] * ew1[l * 3072 + (32 + m) * 64 + j];
            v = acc;
        } else if (k == 36) {
            float acc = eb1[l * 64 + j];
            for (int m = 0; m < 16; m++) acc += eeB[m] * ew1[l * 3072 + (32 + m) * 64 + j];
            v = acc;
        }
        w1b[idx] = f2bf(v);
    }
    if (t0 < 4) {
        float s = 0.f;
        for (int k = 0; k < 16; k++) s += eeW[t0 * 16 + k] * few[k];
        qw[t0] = s;
    } else if (t0 == 4) {
        float s = feb[0];
        for (int k = 0; k < 16; k++) s += eeB[k] * few[k];
        qw[4] = s;
    }
}

// ---------------------------------------------------------------------------
// node init: xb0 = bf16(leak*w+b) ; zero deg, hag
// ---------------------------------------------------------------------------
__global__ __launch_bounds__(256) void node_init_kernel(
    const float* __restrict__ leak, const float* __restrict__ nw, const float* __restrict__ nb,
    unsigned short* __restrict__ xb0, float* __restrict__ hag, int* __restrict__ deg)
{
    int n = blockIdx.x * blockDim.x + threadIdx.x;
    if (n >= NN) return;
    float la = leak[n];
    float v[16];
    #pragma unroll
    for (int i = 0; i < 16; i++) v[i] = la * nw[i] + nb[i];
    unsigned pk[8];
    #pragma unroll
    for (int i = 0; i < 8; i++) pk[i] = pk2(v[2 * i], v[2 * i + 1]);
    uint4* xo = reinterpret_cast<uint4*>(xb0 + n * 16);
    xo[0] = make_uint4(pk[0], pk[1], pk[2], pk[3]);
    xo[1] = make_uint4(pk[4], pk[5], pk[6], pk[7]);
    deg[n] = 0;
    float4 z = {0.f, 0.f, 0.f, 0.f};
    float4* hp = reinterpret_cast<float4*>(hag + n * 64);
    #pragma unroll
    for (int j = 0; j < 16; j++) hp[j] = z;
}

// ---------------------------------------------------------------------------
// edge init: q output + degree histogram; the atomic's return value IS the
// counting-sort rank -> stored for the atomic-free scatter.
// ---------------------------------------------------------------------------
__global__ __launch_bounds__(256) void edge_init_kernel(
    const float* __restrict__ pa, const int* __restrict__ dst,
    const float* __restrict__ qw, float* __restrict__ qout,
    int* __restrict__ deg, int* __restrict__ rank)
{
    int t = blockIdx.x * blockDim.x + threadIdx.x;
    if (t >= NE) return;
    float4 p = reinterpret_cast<const float4*>(pa)[t];
    qout[t] = qw[4] + p.x * qw[0] + p.y * qw[1] + p.z * qw[2] + p.w * qw[3];
    rank[t] = atomicAdd(&deg[dst[t]], 1);
}

// ---------------------------------------------------------------------------
// single-block exclusive scan of deg[NN] -> off[NN+1]
// ---------------------------------------------------------------------------
#define SCAN_T 1024
#define SCAN_C 49
__global__ __launch_bounds__(SCAN_T) void scan_kernel(const int* __restrict__ deg, int* __restrict__ off)
{
    __shared__ int part[SCAN_T];
    int tid = threadIdx.x;
    int base = tid * SCAN_C;
    int s = 0;
    for (int i = 0; i < SCAN_C; i++) {
        int idx = base + i;
        if (idx < NN) s += deg[idx];
    }
    part[tid] = s;
    __syncthreads();
    for (int o = 1; o < SCAN_T; o <<= 1) {
        int v = (tid >= o) ? part[tid - o] : 0;
        __syncthreads();
        part[tid] += v;
        __syncthreads();
    }
    int run = part[tid] - s;
    for (int i = 0; i < SCAN_C; i++) {
        int idx = base + i;
        if (idx < NN) { off[idx] = run; run += deg[idx]; }
    }
    if (tid == SCAN_T - 1) off[NN] = part[SCAN_T - 1];
}

// ---------------------------------------------------------------------------
// scatter (atomic-free): pos = off[dst] + rank; one packed 16B write per edge.
// ---------------------------------------------------------------------------
__global__ __launch_bounds__(256) void scatter_kernel(
    const int* __restrict__ ei, const float* __restrict__ pa,
    const int* __restrict__ off, const int* __restrict__ rank,
    uint4* __restrict__ epk)
{
    int t = blockIdx.x * blockDim.x + threadIdx.x;
    if (t >= NE) return;
    int d = ei[NE + t];
    int pos = off[d] + rank[t];
    float4 p = reinterpret_cast<const float4*>(pa)[t];
    uint4 v;
    v.x = (unsigned)ei[t];
    v.y = (unsigned)d;
    v.z = pk2(p.x, p.y);
    v.w = pk2(p.z, p.w);
    epk[pos] = v;
}

// ---------------------------------------------------------------------------
// MFMA edge kernel. Per wave: 64 dst-sorted edges = 4 tiles of 16 edges.
// All 4 epk loads + all 4 xb gathers issued upfront (max VMEM overlap);
// segment start d0 = dst of first edge (no binary search).
// A-frag: lane l = edge row l&15, k (l>>4)*8+e:
//   K-step 0 = [xd(16), xs(16)] ; K-step 1 = [pa(4), 1, 0...]
// 8 MFMAs/tile vs preloaded B-frags. relu -> bf16 -> LDS h[j=64][edge=64],
// per-wave segmented column-sum -> coalesced f32 atomics into hag[N][64].
// ---------------------------------------------------------------------------
__global__ __launch_bounds__(256, 4) void edge_mfma_kernel(
    const unsigned short* __restrict__ xb,
    const uint4* __restrict__ epk,
    const int* __restrict__ off,
    const unsigned short* __restrict__ w1b,   // this layer's 8 B-frags [8][64][8]
    float* __restrict__ hag)
{
    __shared__ unsigned short hbuf[4][64 * 68];
    int tid = threadIdx.x;
    int lane = tid & 63;
    int wid = tid >> 6;
    int wave = blockIdx.x * 4 + wid;
    int base = wave * 64;                  // NE % 64 == 0
    if (base >= NE) return;
    int ar = lane & 15;
    int ap = lane >> 4;
    unsigned short* hb = &hbuf[wid][0];

    // all edge-record loads upfront (4 independent 16B loads in flight)
    uint4 ev0 = epk[base + 0  + ar];
    uint4 ev1 = epk[base + 16 + ar];
    uint4 ev2 = epk[base + 32 + ar];
    uint4 ev3 = epk[base + 48 + ar];

    // all x-feature gathers upfront (4 more 16B loads in flight)
    int r0 = (ap < 2) ? (int)ev0.y : (int)ev0.x;
    int r1 = (ap < 2) ? (int)ev1.y : (int)ev1.x;
    int r2 = (ap < 2) ? (int)ev2.y : (int)ev2.x;
    int r3 = (ap < 2) ? (int)ev3.y : (int)ev3.x;
    int half = (ap & 1) * 8;
    bf16x8 a00 = *reinterpret_cast<const bf16x8*>(xb + (size_t)r0 * 16 + half);
    bf16x8 a01 = *reinterpret_cast<const bf16x8*>(xb + (size_t)r1 * 16 + half);
    bf16x8 a02 = *reinterpret_cast<const bf16x8*>(xb + (size_t)r2 * 16 + half);
    bf16x8 a03 = *reinterpret_cast<const bf16x8*>(xb + (size_t)r3 * 16 + half);

    // segment start: dst of first edge in range (off[d0] <= base by construction)
    int d0 = __builtin_amdgcn_readfirstlane((int)ev0.y);

    // preload B fragments (8 x 16B)
    bf16x8 Bf[8];
    const bf16x8* w1v = reinterpret_cast<const bf16x8*>(w1b);
    #pragma unroll
    for (int i = 0; i < 8; i++) Bf[i] = w1v[i * 64 + lane];

#define DO_TILE(EV, A0, TILE) do {                                             \
    bf16x8 a1 = (bf16x8)0;                                                     \
    if (ap == 0) {                                                             \
        a1[0] = (short)(EV.z & 0xffffu);                                       \
        a1[1] = (short)(EV.z >> 16);                                           \
        a1[2] = (short)(EV.w & 0xffffu);                                       \
        a1[3] = (short)(EV.w >> 16);                                           \
        a1[4] = (short)0x3f80;                                                 \
    }                                                                          \
    f32x4 C0 = {0.f, 0.f, 0.f, 0.f}, C1 = C0, C2 = C0, C3 = C0;                \
    C0 = __builtin_amdgcn_mfma_f32_16x16x32_bf16(A0, Bf[0], C0, 0, 0, 0);      \
    C0 = __builtin_amdgcn_mfma_f32_16x16x32_bf16(a1, Bf[1], C0, 0, 0, 0);      \
    C1 = __builtin_amdgcn_mfma_f32_16x16x32_bf16(A0, Bf[2], C1, 0, 0, 0);      \
    C1 = __builtin_amdgcn_mfma_f32_16x16x32_bf16(a1, Bf[3], C1, 0, 0, 0);      \
    C2 = __builtin_amdgcn_mfma_f32_16x16x32_bf16(A0, Bf[4], C2, 0, 0, 0);      \
    C2 = __builtin_amdgcn_mfma_f32_16x16x32_bf16(a1, Bf[5], C2, 0, 0, 0);      \
    C3 = __builtin_amdgcn_mfma_f32_16x16x32_bf16(A0, Bf[6], C3, 0, 0, 0);      \
    C3 = __builtin_amdgcn_mfma_f32_16x16x32_bf16(a1, Bf[7], C3, 0, 0, 0);      \
    int eoff = TILE * 16 + ap * 4;                                             \
    {                                                                          \
        unsigned lov = pk2(fmaxf(C0[0], 0.f), fmaxf(C0[1], 0.f));              \
        unsigned hiv = pk2(fmaxf(C0[2], 0.f), fmaxf(C0[3], 0.f));              \
        *reinterpret_cast<uint2*>(hb + (0 * 16 + ar) * 68 + eoff) = make_uint2(lov, hiv); \
    }                                                                          \
    {                                                                          \
        unsigned lov = pk2(fmaxf(C1[0], 0.f), fmaxf(C1[1], 0.f));              \
        unsigned hiv = pk2(fmaxf(C1[2], 0.f), fmaxf(C1[3], 0.f));              \
        *reinterpret_cast<uint2*>(hb + (1 * 16 + ar) * 68 + eoff) = make_uint2(lov, hiv); \
    }                                                                          \
    {                                                                          \
        unsigned lov = pk2(fmaxf(C2[0], 0.f), fmaxf(C2[1], 0.f));              \
        unsigned hiv = pk2(fmaxf(C2[2], 0.f), fmaxf(C2[3], 0.f));              \
        *reinterpret_cast<uint2*>(hb + (2 * 16 + ar) * 68 + eoff) = make_uint2(lov, hiv); \
    }                                                                          \
    {                                                                          \
        unsigned lov = pk2(fmaxf(C3[0], 0.f), fmaxf(C3[1], 0.f));              \
        unsigned hiv = pk2(fmaxf(C3[2], 0.f), fmaxf(C3[3], 0.f));              \
        *reinterpret_cast<uint2*>(hb + (3 * 16 + ar) * 68 + eoff) = make_uint2(lov, hiv); \
    }                                                                          \
} while (0)

    DO_TILE(ev0, a00, 0);
    DO_TILE(ev1, a01, 1);
    DO_TILE(ev2, a02, 2);
    DO_TILE(ev3, a03, 3);
#undef DO_TILE

    asm volatile("s_waitcnt lgkmcnt(0)" ::: "memory");
    __builtin_amdgcn_sched_barrier(0);

    // segmented column-sum: lane owns hidden unit j = lane.
    // Packed uint2 (4 bf16) LDS reads with scalar head/tail at boundaries.
    int d = d0;
    int e = base;
    const int lim = base + 64;
    const unsigned short* hr = hb + lane * 68;
    while (e < lim) {
        int segend = off[d + 1];
        int eend = segend < lim ? segend : lim;
        float acc = 0.f;
        int i = e - base, iend = eend - base;
        for (; (i & 3) != 0 && i < iend; ++i) acc += bf2f(hr[i]);
        for (; i + 4 <= iend; i += 4) {
            uint2 u = *reinterpret_cast<const uint2*>(hr + i);
            acc += __uint_as_float(u.x << 16) + __uint_as_float(u.x & 0xffff0000u)
                 + __uint_as_float(u.y << 16) + __uint_as_float(u.y & 0xffff0000u);
        }
        for (; i < iend; ++i) acc += bf2f(hr[i]);
        unsafeAtomicAdd(&hag[(size_t)d * 64 + lane], acc);
        e = eend;
        if (segend <= lim) ++d;
    }
}

// ---------------------------------------------------------------------------
// node update: aggr = W2^T(hag)/deg + b2 (0 if deg==0), then 32->64->16 MLP.
// Reads/writes bf16 x-tables. Re-zeros hag. Emits H on last layer.
// ---------------------------------------------------------------------------
__global__ __launch_bounds__(256) void node_mlp_kernel(
    const unsigned short* __restrict__ xb, unsigned short* __restrict__ xbn,
    float* __restrict__ hag, const int* __restrict__ off,
    const float* __restrict__ ew2, const float* __restrict__ eb2,
    const float* __restrict__ nw1t, const float* __restrict__ nb1,
    const float* __restrict__ nw2, const float* __restrict__ nb2,
    const float* __restrict__ fnw, const float* __restrict__ fnb,
    float* __restrict__ Hout, int writeH)
{
    int n = blockIdx.x * blockDim.x + threadIdx.x;
    if (n >= NN) return;
    float u[32];
    const uint4* xp = reinterpret_cast<const uint4*>(xb + n * 16);
    uint4 xa = xp[0], xbv = xp[1];
    {
        unsigned w[8] = {xa.x, xa.y, xa.z, xa.w, xbv.x, xbv.y, xbv.z, xbv.w};
        #pragma unroll
        for (int i = 0; i < 8; i++) {
            u[2 * i]     = __uint_as_float(w[i] << 16);
            u[2 * i + 1] = __uint_as_float(w[i] & 0xffff0000u);
        }
    }
    int dg = off[n + 1] - off[n];
    float inv = 1.0f / (float)(dg > 0 ? dg : 1);
    float bsc = (dg > 0) ? 1.0f : 0.0f;
    float tacc[16];
    #pragma unroll
    for (int k = 0; k < 16; k++) tacc[k] = 0.f;
    float4* hp4 = reinterpret_cast<float4*>(hag + (size_t)n * 64);
    #pragma unroll 1
    for (int j4 = 0; j4 < 16; j4++) {
        float4 hv = hp4[j4];
        int j = j4 * 4;
        #pragma unroll
        for (int k = 0; k < 16; k++) {
            tacc[k] += hv.x * ew2[(j + 0) * 16 + k];
            tacc[k] += hv.y * ew2[(j + 1) * 16 + k];
            tacc[k] += hv.z * ew2[(j + 2) * 16 + k];
            tacc[k] += hv.w * ew2[(j + 3) * 16 + k];
        }
    }
    float4 z = {0.f, 0.f, 0.f, 0.f};
    #pragma unroll
    for (int j4 = 0; j4 < 16; j4++) hp4[j4] = z;   // re-zero for next layer
    #pragma unroll
    for (int k = 0; k < 16; k++) u[16 + k] = bsc * eb2[k] + tacc[k] * inv;

    float o[16];
    #pragma unroll
    for (int k = 0; k < 16; k++) o[k] = nb2[k];
    #pragma unroll 1
    for (int j = 0; j < 64; j++) {
        float h = nb1[j];
        const float* wr = nw1t + j * 32;
        #pragma unroll
        for (int i = 0; i < 32; i++) h += u[i] * wr[i];
        h = fmaxf(h, 0.f);
        #pragma unroll
        for (int k = 0; k < 16; k++) o[k] += h * nw2[j * 16 + k];
    }
    unsigned pk[8];
    #pragma unroll
    for (int i = 0; i < 8; i++) pk[i] = pk2(o[2 * i], o[2 * i + 1]);
    uint4* xo = reinterpret_cast<uint4*>(xbn + n * 16);
    xo[0] = make_uint4(pk[0], pk[1], pk[2], pk[3]);
    xo[1] = make_uint4(pk[4], pk[5], pk[6], pk[7]);
    if (writeH) {
        float s = fnb[0];
        #pragma unroll
        for (int k = 0; k < 16; k++) s += o[k] * fnw[k];
        Hout[n] = s;
    }
}

extern "C" void kernel_launch(void* const* d_in, const int* in_sizes, int n_in,
                              void* d_out, int out_size, void* d_ws, size_t ws_size,
                              hipStream_t stream)
{
    const float* leak = (const float*)d_in[0];
    const float* pa   = (const float*)d_in[1];
    const int*   ei   = (const int*)d_in[2];
    const float* neww = (const float*)d_in[3];
    const float* newb = (const float*)d_in[4];
    const float* eeW  = (const float*)d_in[5];
    const float* eeB  = (const float*)d_in[6];
    const float* ew1  = (const float*)d_in[7];
    const float* eb1  = (const float*)d_in[8];
    const float* ew2  = (const float*)d_in[9];
    const float* eb2  = (const float*)d_in[10];
    const float* nw1  = (const float*)d_in[11];
    const float* nb1  = (const float*)d_in[12];
    const float* nw2  = (const float*)d_in[13];
    const float* nb2  = (const float*)d_in[14];
    const float* fnw  = (const float*)d_in[15];
    const float* fnb  = (const float*)d_in[16];
    const float* few  = (const float*)d_in[17];
    const float* feb  = (const float*)d_in[18];

    char* wsb = (char*)d_ws;
    float*          hag  = (float*)(wsb + B_HAG);
    float*          qw   = (float*)(wsb + B_QW);
    float*          w1tn = (float*)(wsb + B_W1TN);
    unsigned short* w1b  = (unsigned short*)(wsb + B_W1B);
    unsigned short* xb0  = (unsigned short*)(wsb + B_XB0);
    unsigned short* xb1  = (unsigned short*)(wsb + B_XB1);
    uint4*          epk  = (uint4*)(wsb + B_EPK);
    int*            deg  = (int*)(wsb + B_DEG);
    int*            rnk  = (int*)(wsb + B_RNK);
    int*            off  = (int*)(wsb + B_OFF);

    float* H = (float*)d_out;
    float* q = (float*)d_out + NN;
    const int* dstp = ei + NE;

    prep_kernel<<<16, 256, 0, stream>>>(ew1, eb1, nw1, eeW, eeB, few, feb,
                                        w1b, w1tn, qw);
    node_init_kernel<<<(NN + 255) / 256, 256, 0, stream>>>(leak, neww, newb, xb0, hag, deg);
    edge_init_kernel<<<(NE + 255) / 256, 256, 0, stream>>>(pa, dstp, qw, q, deg, rnk);
    scan_kernel<<<1, SCAN_T, 0, stream>>>(deg, off);
    scatter_kernel<<<(NE + 255) / 256, 256, 0, stream>>>(ei, pa, off, rnk, epk);

    unsigned short* xcur = xb0;
    unsigned short* xnxt = xb1;
    for (int l = 0; l < 3; l++) {
        edge_mfma_kernel<<<NE / 256, 256, 0, stream>>>(
            xcur, epk, off, w1b + l * 4096, hag);
        node_mlp_kernel<<<(NN + 255) / 256, 256, 0, stream>>>(
            xcur, xnxt, hag, off, ew2 + l * 1024, eb2 + l * 16,
            w1tn + l * 2048, nb1 + l * 64, nw2 + l * 1024, nb2 + l * 16,
            fnw, fnb, H, (l == 2) ? 1 : 0);
        unsigned short* tmp = xcur; xcur = xnxt; xnxt = tmp;
    }
}

// Round 8
// 383.684 us; speedup vs baseline: 3.2523x; 1.2218x over previous
//
#include <hip/hip_runtime.h>
#include <hip/hip_bf16.h>

#define NN 50000
#define NE 1600000
#define SCB 196   // ceil(NN/256) scan blocks; SCB <= 256 so top scan fits one block

typedef __attribute__((ext_vector_type(8))) short bf16x8;
typedef __attribute__((ext_vector_type(4))) float f32x4;

// ---- workspace layout (byte offsets) ----
#define B_HAG   0                              // NN*64 f32 = 12,800,000
#define B_QW    (B_HAG + NN*64*4)              // 8 f32 (pad to 32B)
#define B_W1TN  (B_QW + 32)                    // 3*64*32 f32
#define B_W1B   (B_W1TN + 3*64*32*4)           // 3*8*64*8 bf16 (packed B-frags)
#define B_XB0   (B_W1B + 3*8*64*8*2)           // NN*16 bf16
#define B_XB1   (B_XB0 + NN*16*2)              // NN*16 bf16
#define B_EPK   (B_XB1 + NN*16*2)              // NE uint4 packed {src,dst,pa01,pa23}
#define B_DEG   (B_EPK + NE*16)                // NN int
#define B_RNK   (B_DEG + NN*4)                 // NE int (sort rank per edge)
#define B_OFF   (B_RNK + NE*4)                 // NN+1 int
#define B_PART  (B_OFF + (NN+1)*4)             // SCB int (scan partials)
#define B_END   (B_PART + SCB*4)               // ~48.3 MB

static __device__ __forceinline__ unsigned short f2bf(float f) {
    union { __hip_bfloat16 h; unsigned short u; } cv;
    cv.h = __float2bfloat16(f);
    return cv.u;
}
static __device__ __forceinline__ unsigned pk2(float a, float b) {
    unsigned r;
    asm("v_cvt_pk_bf16_f32 %0, %1, %2" : "=v"(r) : "v"(a), "v"(b));
    return r;
}
static __device__ __forceinline__ float bf2f(unsigned short u) {
    return __uint_as_float((unsigned)u << 16);
}

// ---------------------------------------------------------------------------
// prep: build packed MFMA B-operand w1b[l][frag=t*2+s][lane][e] covering the
// folded edge stage-1 weight matrix W1ext[K=64][N=64]:
//   k 0..15  = W1 rows for x_dst ; k 16..31 = W1 rows for x_src ;
//   k 32..35 = Mm (edge-embed fold) ; k 36 = c0 (bias via const-1 col) ; else 0.
// Also: node W1 transpose, q-collapse weights.
// ---------------------------------------------------------------------------
__global__ void prep_kernel(const float* __restrict__ ew1, const float* __restrict__ eb1,
                            const float* __restrict__ nw1,
                            const float* __restrict__ eeW, const float* __restrict__ eeB,
                            const float* __restrict__ few, const float* __restrict__ feb,
                            unsigned short* __restrict__ w1b, float* __restrict__ w1tn,
                            float* __restrict__ qw)
{
    int t0 = blockIdx.x * blockDim.x + threadIdx.x;
    int stride = gridDim.x * blockDim.x;
    for (int idx = t0; idx < 3 * 64 * 32; idx += stride) {
        int l = idx / 2048, r = idx % 2048, j = r / 32, i = r % 32;
        w1tn[idx] = nw1[l * 2048 + i * 64 + j];   // node_mlp_w1 [3][32][64] -> [3][64][32]
    }
    for (int idx = t0; idx < 3 * 8 * 64 * 8; idx += stride) {
        int l = idx >> 12;
        int r = idx & 4095;
        int f = r >> 9;               // frag 0..7 = t*2+s
        int lane = (r >> 3) & 63;
        int e = r & 7;
        int tt = f >> 1, s = f & 1;
        int k = ((lane >> 4) << 3) + e + (s << 5);
        int j = (tt << 4) + (lane & 15);
        float v = 0.f;
        if (k < 32) {
            v = ew1[l * 3072 + k * 64 + j];
        } else if (k < 36) {
            int f2 = k - 32;
            float acc = 0.f;
            for (int m = 0; m < 16; m++) acc += eeW[f2 * 16 + m] * ew1[l * 3072 + (32 + m) * 64 + j];
            v = acc;
        } else if (k == 36) {
            float acc = eb1[l * 64 + j];
            for (int m = 0; m < 16; m++) acc += eeB[m] * ew1[l * 3072 + (32 + m) * 64 + j];
            v = acc;
        }
        w1b[idx] = f2bf(v);
    }
    if (t0 < 4) {
        float s = 0.f;
        for (int k = 0; k < 16; k++) s += eeW[t0 * 16 + k] * few[k];
        qw[t0] = s;
    } else if (t0 == 4) {
        float s = feb[0];
        for (int k = 0; k < 16; k++) s += eeB[k] * few[k];
        qw[4] = s;
    }
}

// ---------------------------------------------------------------------------
// node init: xb0 = bf16(leak*w+b) ; zero deg, hag
// ---------------------------------------------------------------------------
__global__ __launch_bounds__(256) void node_init_kernel(
    const float* __restrict__ leak, const float* __restrict__ nw, const float* __restrict__ nb,
    unsigned short* __restrict__ xb0, float* __restrict__ hag, int* __restrict__ deg)
{
    int n = blockIdx.x * blockDim.x + threadIdx.x;
    if (n >= NN) return;
    float la = leak[n];
    float v[16];
    #pragma unroll
    for (int i = 0; i < 16; i++) v[i] = la * nw[i] + nb[i];
    unsigned pk[8];
    #pragma unroll
    for (int i = 0; i < 8; i++) pk[i] = pk2(v[2 * i], v[2 * i + 1]);
    uint4* xo = reinterpret_cast<uint4*>(xb0 + n * 16);
    xo[0] = make_uint4(pk[0], pk[1], pk[2], pk[3]);
    xo[1] = make_uint4(pk[4], pk[5], pk[6], pk[7]);
    deg[n] = 0;
    float4 z = {0.f, 0.f, 0.f, 0.f};
    float4* hp = reinterpret_cast<float4*>(hag + n * 64);
    #pragma unroll
    for (int j = 0; j < 16; j++) hp[j] = z;
}

// ---------------------------------------------------------------------------
// edge init: q output + degree histogram; the atomic's return value IS the
// counting-sort rank -> stored for the atomic-free scatter.
// ---------------------------------------------------------------------------
__global__ __launch_bounds__(256) void edge_init_kernel(
    const float* __restrict__ pa, const int* __restrict__ dst,
    const float* __restrict__ qw, float* __restrict__ qout,
    int* __restrict__ deg, int* __restrict__ rank)
{
    int t = blockIdx.x * blockDim.x + threadIdx.x;
    if (t >= NE) return;
    float4 p = reinterpret_cast<const float4*>(pa)[t];
    qout[t] = qw[4] + p.x * qw[0] + p.y * qw[1] + p.z * qw[2] + p.w * qw[3];
    rank[t] = atomicAdd(&deg[dst[t]], 1);
}

// ---------------------------------------------------------------------------
// three-phase multi-block exclusive scan of deg[NN] -> off[NN+1]
// ---------------------------------------------------------------------------
__global__ __launch_bounds__(256) void scan_part_kernel(
    const int* __restrict__ deg, int* __restrict__ part)
{
    __shared__ int ws[4];
    int i = blockIdx.x * 256 + threadIdx.x;
    int v = (i < NN) ? deg[i] : 0;
    #pragma unroll
    for (int o = 32; o > 0; o >>= 1) v += __shfl_down(v, o, 64);
    int lane = threadIdx.x & 63, wid = threadIdx.x >> 6;
    if (lane == 0) ws[wid] = v;
    __syncthreads();
    if (threadIdx.x == 0) part[blockIdx.x] = ws[0] + ws[1] + ws[2] + ws[3];
}

__global__ __launch_bounds__(256) void scan_top_kernel(int* __restrict__ part)
{
    __shared__ int sm[256];
    int tid = threadIdx.x;
    int v = (tid < SCB) ? part[tid] : 0;
    sm[tid] = v;
    __syncthreads();
    #pragma unroll
    for (int o = 1; o < 256; o <<= 1) {
        int t = (tid >= o) ? sm[tid - o] : 0;
        __syncthreads();
        sm[tid] += t;
        __syncthreads();
    }
    if (tid < SCB) part[tid] = sm[tid] - v;   // exclusive prefix of block sums
}

__global__ __launch_bounds__(256) void scan_final_kernel(
    const int* __restrict__ deg, const int* __restrict__ part, int* __restrict__ off)
{
    __shared__ int sm[256];
    int tid = threadIdx.x;
    int i = blockIdx.x * 256 + tid;
    int v = (i < NN) ? deg[i] : 0;
    sm[tid] = v;
    __syncthreads();
    #pragma unroll
    for (int o = 1; o < 256; o <<= 1) {
        int t = (tid >= o) ? sm[tid - o] : 0;
        __syncthreads();
        sm[tid] += t;
        __syncthreads();
    }
    int excl = sm[tid] - v + part[blockIdx.x];
    if (i < NN) off[i] = excl;
    if (i == NN - 1) off[NN] = excl + v;
}

// ---------------------------------------------------------------------------
// scatter (atomic-free): pos = off[dst] + rank; one packed 16B write per edge.
// ---------------------------------------------------------------------------
__global__ __launch_bounds__(256) void scatter_kernel(
    const int* __restrict__ ei, const float* __restrict__ pa,
    const int* __restrict__ off, const int* __restrict__ rank,
    uint4* __restrict__ epk)
{
    int t = blockIdx.x * blockDim.x + threadIdx.x;
    if (t >= NE) return;
    int d = ei[NE + t];
    int pos = off[d] + rank[t];
    float4 p = reinterpret_cast<const float4*>(pa)[t];
    uint4 v;
    v.x = (unsigned)ei[t];
    v.y = (unsigned)d;
    v.z = pk2(p.x, p.y);
    v.w = pk2(p.z, p.w);
    epk[pos] = v;
}

// ---------------------------------------------------------------------------
// MFMA edge kernel. Per wave: 64 dst-sorted edges = 4 tiles of 16 edges.
// All 4 epk loads + all 4 xb gathers issued upfront (max VMEM overlap);
// segment start d0 = dst of first edge (no binary search).
// A-frag: lane l = edge row l&15, k (l>>4)*8+e:
//   K-step 0 = [xd(16), xs(16)] ; K-step 1 = [pa(4), 1, 0...]
// 8 MFMAs/tile vs preloaded B-frags. relu -> bf16 -> LDS h[j=64][edge=64],
// per-wave segmented column-sum -> coalesced f32 atomics into hag[N][64].
// ---------------------------------------------------------------------------
__global__ __launch_bounds__(256, 4) void edge_mfma_kernel(
    const unsigned short* __restrict__ xb,
    const uint4* __restrict__ epk,
    const int* __restrict__ off,
    const unsigned short* __restrict__ w1b,   // this layer's 8 B-frags [8][64][8]
    float* __restrict__ hag)
{
    __shared__ unsigned short hbuf[4][64 * 68];
    int tid = threadIdx.x;
    int lane = tid & 63;
    int wid = tid >> 6;
    int wave = blockIdx.x * 4 + wid;
    int base = wave * 64;                  // NE % 64 == 0
    if (base >= NE) return;
    int ar = lane & 15;
    int ap = lane >> 4;
    unsigned short* hb = &hbuf[wid][0];

    // all edge-record loads upfront (4 independent 16B loads in flight)
    uint4 ev0 = epk[base + 0  + ar];
    uint4 ev1 = epk[base + 16 + ar];
    uint4 ev2 = epk[base + 32 + ar];
    uint4 ev3 = epk[base + 48 + ar];

    // all x-feature gathers upfront (4 more 16B loads in flight)
    int r0 = (ap < 2) ? (int)ev0.y : (int)ev0.x;
    int r1 = (ap < 2) ? (int)ev1.y : (int)ev1.x;
    int r2 = (ap < 2) ? (int)ev2.y : (int)ev2.x;
    int r3 = (ap < 2) ? (int)ev3.y : (int)ev3.x;
    int half = (ap & 1) * 8;
    bf16x8 a00 = *reinterpret_cast<const bf16x8*>(xb + (size_t)r0 * 16 + half);
    bf16x8 a01 = *reinterpret_cast<const bf16x8*>(xb + (size_t)r1 * 16 + half);
    bf16x8 a02 = *reinterpret_cast<const bf16x8*>(xb + (size_t)r2 * 16 + half);
    bf16x8 a03 = *reinterpret_cast<const bf16x8*>(xb + (size_t)r3 * 16 + half);

    // segment start: dst of first edge in range (off[d0] <= base by construction)
    int d0 = __builtin_amdgcn_readfirstlane((int)ev0.y);

    // preload B fragments (8 x 16B)
    bf16x8 Bf[8];
    const bf16x8* w1v = reinterpret_cast<const bf16x8*>(w1b);
    #pragma unroll
    for (int i = 0; i < 8; i++) Bf[i] = w1v[i * 64 + lane];

#define DO_TILE(EV, A0, TILE) do {                                             \
    bf16x8 a1 = (bf16x8)0;                                                     \
    if (ap == 0) {                                                             \
        a1[0] = (short)(EV.z & 0xffffu);                                       \
        a1[1] = (short)(EV.z >> 16);                                           \
        a1[2] = (short)(EV.w & 0xffffu);                                       \
        a1[3] = (short)(EV.w >> 16);                                           \
        a1[4] = (short)0x3f80;                                                 \
    }                                                                          \
    f32x4 C0 = {0.f, 0.f, 0.f, 0.f}, C1 = C0, C2 = C0, C3 = C0;                \
    C0 = __builtin_amdgcn_mfma_f32_16x16x32_bf16(A0, Bf[0], C0, 0, 0, 0);      \
    C0 = __builtin_amdgcn_mfma_f32_16x16x32_bf16(a1, Bf[1], C0, 0, 0, 0);      \
    C1 = __builtin_amdgcn_mfma_f32_16x16x32_bf16(A0, Bf[2], C1, 0, 0, 0);      \
    C1 = __builtin_amdgcn_mfma_f32_16x16x32_bf16(a1, Bf[3], C1, 0, 0, 0);      \
    C2 = __builtin_amdgcn_mfma_f32_16x16x32_bf16(A0, Bf[4], C2, 0, 0, 0);      \
    C2 = __builtin_amdgcn_mfma_f32_16x16x32_bf16(a1, Bf[5], C2, 0, 0, 0);      \
    C3 = __builtin_amdgcn_mfma_f32_16x16x32_bf16(A0, Bf[6], C3, 0, 0, 0);      \
    C3 = __builtin_amdgcn_mfma_f32_16x16x32_bf16(a1, Bf[7], C3, 0, 0, 0);      \
    int eoff = TILE * 16 + ap * 4;                                             \
    {                                                                          \
        unsigned lov = pk2(fmaxf(C0[0], 0.f), fmaxf(C0[1], 0.f));              \
        unsigned hiv = pk2(fmaxf(C0[2], 0.f), fmaxf(C0[3], 0.f));              \
        *reinterpret_cast<uint2*>(hb + (0 * 16 + ar) * 68 + eoff) = make_uint2(lov, hiv); \
    }                                                                          \
    {                                                                          \
        unsigned lov = pk2(fmaxf(C1[0], 0.f), fmaxf(C1[1], 0.f));              \
        unsigned hiv = pk2(fmaxf(C1[2], 0.f), fmaxf(C1[3], 0.f));              \
        *reinterpret_cast<uint2*>(hb + (1 * 16 + ar) * 68 + eoff) = make_uint2(lov, hiv); \
    }                                                                          \
    {                                                                          \
        unsigned lov = pk2(fmaxf(C2[0], 0.f), fmaxf(C2[1], 0.f));              \
        unsigned hiv = pk2(fmaxf(C2[2], 0.f), fmaxf(C2[3], 0.f));              \
        *reinterpret_cast<uint2*>(hb + (2 * 16 + ar) * 68 + eoff) = make_uint2(lov, hiv); \
    }                                                                          \
    {                                                                          \
        unsigned lov = pk2(fmaxf(C3[0], 0.f), fmaxf(C3[1], 0.f));              \
        unsigned hiv = pk2(fmaxf(C3[2], 0.f), fmaxf(C3[3], 0.f));              \
        *reinterpret_cast<uint2*>(hb + (3 * 16 + ar) * 68 + eoff) = make_uint2(lov, hiv); \
    }                                                                          \
} while (0)

    DO_TILE(ev0, a00, 0);
    DO_TILE(ev1, a01, 1);
    DO_TILE(ev2, a02, 2);
    DO_TILE(ev3, a03, 3);
#undef DO_TILE

    asm volatile("s_waitcnt lgkmcnt(0)" ::: "memory");
    __builtin_amdgcn_sched_barrier(0);

    // segmented column-sum: lane owns hidden unit j = lane.
    // Packed uint2 (4 bf16) LDS reads with scalar head/tail at boundaries.
    int d = d0;
    int e = base;
    const int lim = base + 64;
    const unsigned short* hr = hb + lane * 68;
    while (e < lim) {
        int segend = off[d + 1];
        int eend = segend < lim ? segend : lim;
        float acc = 0.f;
        int i = e - base, iend = eend - base;
        for (; (i & 3) != 0 && i < iend; ++i) acc += bf2f(hr[i]);
        for (; i + 4 <= iend; i += 4) {
            uint2 u = *reinterpret_cast<const uint2*>(hr + i);
            acc += __uint_as_float(u.x << 16) + __uint_as_float(u.x & 0xffff0000u)
                 + __uint_as_float(u.y << 16) + __uint_as_float(u.y & 0xffff0000u);
        }
        for (; i < iend; ++i) acc += bf2f(hr[i]);
        unsafeAtomicAdd(&hag[(size_t)d * 64 + lane], acc);
        e = eend;
        if (segend <= lim) ++d;
    }
}

// ---------------------------------------------------------------------------
// node update: aggr = W2^T(hag)/deg + b2 (0 if deg==0), then 32->64->16 MLP.
// Reads/writes bf16 x-tables. Re-zeros hag. Emits H on last layer.
// ---------------------------------------------------------------------------
__global__ __launch_bounds__(256) void node_mlp_kernel(
    const unsigned short* __restrict__ xb, unsigned short* __restrict__ xbn,
    float* __restrict__ hag, const int* __restrict__ off,
    const float* __restrict__ ew2, const float* __restrict__ eb2,
    const float* __restrict__ nw1t, const float* __restrict__ nb1,
    const float* __restrict__ nw2, const float* __restrict__ nb2,
    const float* __restrict__ fnw, const float* __restrict__ fnb,
    float* __restrict__ Hout, int writeH)
{
    int n = blockIdx.x * blockDim.x + threadIdx.x;
    if (n >= NN) return;
    float u[32];
    const uint4* xp = reinterpret_cast<const uint4*>(xb + n * 16);
    uint4 xa = xp[0], xbv = xp[1];
    {
        unsigned w[8] = {xa.x, xa.y, xa.z, xa.w, xbv.x, xbv.y, xbv.z, xbv.w};
        #pragma unroll
        for (int i = 0; i < 8; i++) {
            u[2 * i]     = __uint_as_float(w[i] << 16);
            u[2 * i + 1] = __uint_as_float(w[i] & 0xffff0000u);
        }
    }
    int dg = off[n + 1] - off[n];
    float inv = 1.0f / (float)(dg > 0 ? dg : 1);
    float bsc = (dg > 0) ? 1.0f : 0.0f;
    float tacc[16];
    #pragma unroll
    for (int k = 0; k < 16; k++) tacc[k] = 0.f;
    float4* hp4 = reinterpret_cast<float4*>(hag + (size_t)n * 64);
    #pragma unroll 1
    for (int j4 = 0; j4 < 16; j4++) {
        float4 hv = hp4[j4];
        int j = j4 * 4;
        #pragma unroll
        for (int k = 0; k < 16; k++) {
            tacc[k] += hv.x * ew2[(j + 0) * 16 + k];
            tacc[k] += hv.y * ew2[(j + 1) * 16 + k];
            tacc[k] += hv.z * ew2[(j + 2) * 16 + k];
            tacc[k] += hv.w * ew2[(j + 3) * 16 + k];
        }
    }
    float4 z = {0.f, 0.f, 0.f, 0.f};
    #pragma unroll
    for (int j4 = 0; j4 < 16; j4++) hp4[j4] = z;   // re-zero for next layer
    #pragma unroll
    for (int k = 0; k < 16; k++) u[16 + k] = bsc * eb2[k] + tacc[k] * inv;

    float o[16];
    #pragma unroll
    for (int k = 0; k < 16; k++) o[k] = nb2[k];
    #pragma unroll 1
    for (int j = 0; j < 64; j++) {
        float h = nb1[j];
        const float* wr = nw1t + j * 32;
        #pragma unroll
        for (int i = 0; i < 32; i++) h += u[i] * wr[i];
        h = fmaxf(h, 0.f);
        #pragma unroll
        for (int k = 0; k < 16; k++) o[k] += h * nw2[j * 16 + k];
    }
    unsigned pk[8];
    #pragma unroll
    for (int i = 0; i < 8; i++) pk[i] = pk2(o[2 * i], o[2 * i + 1]);
    uint4* xo = reinterpret_cast<uint4*>(xbn + n * 16);
    xo[0] = make_uint4(pk[0], pk[1], pk[2], pk[3]);
    xo[1] = make_uint4(pk[4], pk[5], pk[6], pk[7]);
    if (writeH) {
        float s = fnb[0];
        #pragma unroll
        for (int k = 0; k < 16; k++) s += o[k] * fnw[k];
        Hout[n] = s;
    }
}

extern "C" void kernel_launch(void* const* d_in, const int* in_sizes, int n_in,
                              void* d_out, int out_size, void* d_ws, size_t ws_size,
                              hipStream_t stream)
{
    const float* leak = (const float*)d_in[0];
    const float* pa   = (const float*)d_in[1];
    const int*   ei   = (const int*)d_in[2];
    const float* neww = (const float*)d_in[3];
    const float* newb = (const float*)d_in[4];
    const float* eeW  = (const float*)d_in[5];
    const float* eeB  = (const float*)d_in[6];
    const float* ew1  = (const float*)d_in[7];
    const float* eb1  = (const float*)d_in[8];
    const float* ew2  = (const float*)d_in[9];
    const float* eb2  = (const float*)d_in[10];
    const float* nw1  = (const float*)d_in[11];
    const float* nb1  = (const float*)d_in[12];
    const float* nw2  = (const float*)d_in[13];
    const float* nb2  = (const float*)d_in[14];
    const float* fnw  = (const float*)d_in[15];
    const float* fnb  = (const float*)d_in[16];
    const float* few  = (const float*)d_in[17];
    const float* feb  = (const float*)d_in[18];

    char* wsb = (char*)d_ws;
    float*          hag  = (float*)(wsb + B_HAG);
    float*          qw   = (float*)(wsb + B_QW);
    float*          w1tn = (float*)(wsb + B_W1TN);
    unsigned short* w1b  = (unsigned short*)(wsb + B_W1B);
    unsigned short* xb0  = (unsigned short*)(wsb + B_XB0);
    unsigned short* xb1  = (unsigned short*)(wsb + B_XB1);
    uint4*          epk  = (uint4*)(wsb + B_EPK);
    int*            deg  = (int*)(wsb + B_DEG);
    int*            rnk  = (int*)(wsb + B_RNK);
    int*            off  = (int*)(wsb + B_OFF);
    int*            part = (int*)(wsb + B_PART);

    float* H = (float*)d_out;
    float* q = (float*)d_out + NN;
    const int* dstp = ei + NE;

    prep_kernel<<<16, 256, 0, stream>>>(ew1, eb1, nw1, eeW, eeB, few, feb,
                                        w1b, w1tn, qw);
    node_init_kernel<<<(NN + 255) / 256, 256, 0, stream>>>(leak, neww, newb, xb0, hag, deg);
    edge_init_kernel<<<(NE + 255) / 256, 256, 0, stream>>>(pa, dstp, qw, q, deg, rnk);
    scan_part_kernel<<<SCB, 256, 0, stream>>>(deg, part);
    scan_top_kernel<<<1, 256, 0, stream>>>(part);
    scan_final_kernel<<<SCB, 256, 0, stream>>>(deg, part, off);
    scatter_kernel<<<(NE + 255) / 256, 256, 0, stream>>>(ei, pa, off, rnk, epk);

    unsigned short* xcur = xb0;
    unsigned short* xnxt = xb1;
    for (int l = 0; l < 3; l++) {
        edge_mfma_kernel<<<NE / 256, 256, 0, stream>>>(
            xcur, epk, off, w1b + l * 4096, hag);
        node_mlp_kernel<<<(NN + 255) / 256, 256, 0, stream>>>(
            xcur, xnxt, hag, off, ew2 + l * 1024, eb2 + l * 16,
            w1tn + l * 2048, nb1 + l * 64, nw2 + l * 1024, nb2 + l * 16,
            fnw, fnb, H, (l == 2) ? 1 : 0);
        unsigned short* tmp = xcur; xcur = xnxt; xnxt = tmp;
    }
}

// Round 9
// 341.213 us; speedup vs baseline: 3.6571x; 1.1245x over previous
//
#include <hip/hip_runtime.h>
#include <hip/hip_bf16.h>

#define NN 50000
#define NE 1600000
#define NB 391          // coarse buckets: dst>>7  (49999>>7 = 390)
#define CBLK 98         // count/scatter blocks; 98*16384 >= NE
#define EPB 16384       // edges per count/scatter block (1024 thr x 16)

typedef __attribute__((ext_vector_type(8))) short bf16x8;
typedef __attribute__((ext_vector_type(4))) float f32x4;

// ---- workspace layout (byte offsets) ----
#define B_HAG   0                              // NN*64 f32 = 12,800,000
#define B_QW    (B_HAG + NN*64*4)              // 8 f32
#define B_W1TN  (B_QW + 32)                    // 3*64*32 f32
#define B_W1B   (B_W1TN + 3*64*32*4)           // 3*8*64*8 bf16
#define B_XB0   (B_W1B + 3*8*64*8*2)           // NN*16 bf16
#define B_XB1   (B_XB0 + NN*16*2)              // NN*16 bf16
#define B_EPK   (B_XB1 + NN*16*2)              // NE uint4 {src,dst,pa01,pa23}
#define B_OFF   (B_EPK + NE*16)                // NN+1 int
#define B_BCNT  (B_OFF + (NN+1)*4)             // CBLK*NB int (-> off2 in place)
#define B_BASE  (B_BCNT + CBLK*NB*4)           // NB+1 int
#define B_END   (B_BASE + (NB+1)*4)            // ~42.3 MB

static __device__ __forceinline__ unsigned short f2bf(float f) {
    union { __hip_bfloat16 h; unsigned short u; } cv;
    cv.h = __float2bfloat16(f);
    return cv.u;
}
static __device__ __forceinline__ unsigned pk2(float a, float b) {
    unsigned r;
    asm("v_cvt_pk_bf16_f32 %0, %1, %2" : "=v"(r) : "v"(a), "v"(b));
    return r;
}
static __device__ __forceinline__ float bf2f(unsigned short u) {
    return __uint_as_float((unsigned)u << 16);
}

// ---------------------------------------------------------------------------
// prep: packed MFMA B-operand w1b (folded W1ext[K=64][N=64]), node W1
// transpose, q-collapse weights. (unchanged from R8)
// ---------------------------------------------------------------------------
__global__ void prep_kernel(const float* __restrict__ ew1, const float* __restrict__ eb1,
                            const float* __restrict__ nw1,
                            const float* __restrict__ eeW, const float* __restrict__ eeB,
                            const float* __restrict__ few, const float* __restrict__ feb,
                            unsigned short* __restrict__ w1b, float* __restrict__ w1tn,
                            float* __restrict__ qw)
{
    int t0 = blockIdx.x * blockDim.x + threadIdx.x;
    int stride = gridDim.x * blockDim.x;
    for (int idx = t0; idx < 3 * 64 * 32; idx += stride) {
        int l = idx / 2048, r = idx % 2048, j = r / 32, i = r % 32;
        w1tn[idx] = nw1[l * 2048 + i * 64 + j];
    }
    for (int idx = t0; idx < 3 * 8 * 64 * 8; idx += stride) {
        int l = idx >> 12;
        int r = idx & 4095;
        int f = r >> 9;
        int lane = (r >> 3) & 63;
        int e = r & 7;
        int tt = f >> 1, s = f & 1;
        int k = ((lane >> 4) << 3) + e + (s << 5);
        int j = (tt << 4) + (lane & 15);
        float v = 0.f;
        if (k < 32) {
            v = ew1[l * 3072 + k * 64 + j];
        } else if (k < 36) {
            int f2 = k - 32;
            float acc = 0.f;
            for (int m = 0; m < 16; m++) acc += eeW[f2 * 16 + m] * ew1[l * 3072 + (32 + m) * 64 + j];
            v = acc;
        } else if (k == 36) {
            float acc = eb1[l * 64 + j];
            for (int m = 0; m < 16; m++) acc += eeB[m] * ew1[l * 3072 + (32 + m) * 64 + j];
            v = acc;
        }
        w1b[idx] = f2bf(v);
    }
    if (t0 < 4) {
        float s = 0.f;
        for (int k = 0; k < 16; k++) s += eeW[t0 * 16 + k] * few[k];
        qw[t0] = s;
    } else if (t0 == 4) {
        float s = feb[0];
        for (int k = 0; k < 16; k++) s += eeB[k] * few[k];
        qw[4] = s;
    }
}

// ---------------------------------------------------------------------------
// node init: xb0 = bf16(leak*w+b) ; zero hag
// ---------------------------------------------------------------------------
__global__ __launch_bounds__(256) void node_init_kernel(
    const float* __restrict__ leak, const float* __restrict__ nw, const float* __restrict__ nb,
    unsigned short* __restrict__ xb0, float* __restrict__ hag)
{
    int n = blockIdx.x * blockDim.x + threadIdx.x;
    if (n >= NN) return;
    float la = leak[n];
    float v[16];
    #pragma unroll
    for (int i = 0; i < 16; i++) v[i] = la * nw[i] + nb[i];
    unsigned pk[8];
    #pragma unroll
    for (int i = 0; i < 8; i++) pk[i] = pk2(v[2 * i], v[2 * i + 1]);
    uint4* xo = reinterpret_cast<uint4*>(xb0 + n * 16);
    xo[0] = make_uint4(pk[0], pk[1], pk[2], pk[3]);
    xo[1] = make_uint4(pk[4], pk[5], pk[6], pk[7]);
    float4 z = {0.f, 0.f, 0.f, 0.f};
    float4* hp = reinterpret_cast<float4*>(hag + n * 64);
    #pragma unroll
    for (int j = 0; j < 16; j++) hp[j] = z;
}

// ---------------------------------------------------------------------------
// A: coarse bucket count via LDS histogram (no global atomics)
// ---------------------------------------------------------------------------
__global__ __launch_bounds__(1024) void bucket_count_kernel(
    const int* __restrict__ dst, int* __restrict__ bcnt)
{
    __shared__ int hist[NB];
    int t = threadIdx.x;
    for (int i = t; i < NB; i += 1024) hist[i] = 0;
    __syncthreads();
    int base = blockIdx.x * EPB;
    #pragma unroll
    for (int i = 0; i < 16; i++) {
        int idx = base + i * 1024 + t;
        if (idx < NE) atomicAdd(&hist[dst[idx] >> 7], 1);
    }
    __syncthreads();
    for (int i = t; i < NB; i += 1024) bcnt[blockIdx.x * NB + i] = hist[i];
}

// ---------------------------------------------------------------------------
// B: scan bcnt[CBLK][NB] -> off2 (in place) + bucket bases gbase[NB+1]
// ---------------------------------------------------------------------------
__global__ __launch_bounds__(512) void bucket_scan_kernel(
    int* __restrict__ bcnt, int* __restrict__ gbase)
{
    __shared__ int sm[512];
    int t = threadIdx.x;
    int tot = 0;
    if (t < NB)
        for (int blk = 0; blk < CBLK; blk++) tot += bcnt[blk * NB + t];
    sm[t] = tot;
    __syncthreads();
    for (int o = 1; o < 512; o <<= 1) {
        int v = (t >= o) ? sm[t - o] : 0;
        __syncthreads();
        sm[t] += v;
        __syncthreads();
    }
    int excl = sm[t] - tot;
    if (t < NB) {
        gbase[t] = excl;
        int run = excl;
        for (int blk = 0; blk < CBLK; blk++) {
            int c = bcnt[blk * NB + t];
            bcnt[blk * NB + t] = run;
            run += c;
        }
    }
    if (t == 0) gbase[NB] = NE;
}

// ---------------------------------------------------------------------------
// C: coarse scatter. LDS-atomic local rank (matches A's counts), plus q.
// pos = off2[blk][bucket] + lrank -> bucket-contiguous packed records.
// ---------------------------------------------------------------------------
__global__ __launch_bounds__(1024) void bucket_scatter_kernel(
    const int* __restrict__ ei, const float* __restrict__ pa,
    const int* __restrict__ bcnt, const float* __restrict__ qw,
    float* __restrict__ qout, uint4* __restrict__ epk)
{
    __shared__ int hist[NB];
    int t = threadIdx.x;
    for (int i = t; i < NB; i += 1024) hist[i] = 0;
    __syncthreads();
    int base = blockIdx.x * EPB;
    #pragma unroll
    for (int i = 0; i < 16; i++) {
        int idx = base + i * 1024 + t;
        if (idx < NE) {
            int d = ei[NE + idx];
            int b = d >> 7;
            float4 p = reinterpret_cast<const float4*>(pa)[idx];
            qout[idx] = qw[4] + p.x * qw[0] + p.y * qw[1] + p.z * qw[2] + p.w * qw[3];
            int lr = atomicAdd(&hist[b], 1);
            int pos = bcnt[blockIdx.x * NB + b] + lr;
            uint4 v;
            v.x = (unsigned)ei[idx];
            v.y = (unsigned)d;
            v.z = pk2(p.x, p.y);
            v.w = pk2(p.z, p.w);
            epk[pos] = v;
        }
    }
}

// ---------------------------------------------------------------------------
// D: fine sort within each coarse bucket, in place (records held in regs),
// and emit off[]. Bucket size <= 12288 (avg 4096, sigma 64 -> 128-sigma
// margin for this fixed input).
// ---------------------------------------------------------------------------
__global__ __launch_bounds__(1024) void fine_sort_kernel(
    const int* __restrict__ gbase, uint4* __restrict__ epk, int* __restrict__ off)
{
    __shared__ int hist[128];
    __shared__ int fb[128];
    int t = threadIdx.x;
    int b = blockIdx.x;
    int S = gbase[b], E = gbase[b + 1];
    if (t < 128) hist[t] = 0;
    __syncthreads();

    uint4 r[12];
    int lr[12];
    #pragma unroll
    for (int i = 0; i < 12; i++) {
        int gi = S + i * 1024 + t;
        if (gi < E) {
            r[i] = epk[gi];
            lr[i] = atomicAdd(&hist[(int)(r[i].y & 127u)], 1);
        }
    }
    __syncthreads();
    if (t < 128) fb[t] = hist[t];
    __syncthreads();
    for (int o = 1; o < 128; o <<= 1) {
        int v = 0;
        if (t < 128 && t >= o) v = fb[t - o];
        __syncthreads();
        if (t < 128) fb[t] += v;
        __syncthreads();
    }
    // fb inclusive; exclusive base = fb - hist
    int d0 = b << 7;
    if (t < 128 && d0 + t < NN) off[d0 + t] = S + fb[t] - hist[t];
    if (b == NB - 1 && t == 0) off[NN] = NE;
    __syncthreads();
    #pragma unroll
    for (int i = 0; i < 12; i++) {
        int gi = S + i * 1024 + t;
        if (gi < E) {
            int fd = (int)(r[i].y & 127u);
            int pos = S + (fb[fd] - hist[fd]) + lr[i];
            epk[pos] = r[i];
        }
    }
}

// ---------------------------------------------------------------------------
// MFMA edge kernel (unchanged from R8). Per wave: 64 dst-sorted edges.
// ---------------------------------------------------------------------------
__global__ __launch_bounds__(256, 4) void edge_mfma_kernel(
    const unsigned short* __restrict__ xb,
    const uint4* __restrict__ epk,
    const int* __restrict__ off,
    const unsigned short* __restrict__ w1b,
    float* __restrict__ hag)
{
    __shared__ unsigned short hbuf[4][64 * 68];
    int tid = threadIdx.x;
    int lane = tid & 63;
    int wid = tid >> 6;
    int wave = blockIdx.x * 4 + wid;
    int base = wave * 64;
    if (base >= NE) return;
    int ar = lane & 15;
    int ap = lane >> 4;
    unsigned short* hb = &hbuf[wid][0];

    uint4 ev0 = epk[base + 0  + ar];
    uint4 ev1 = epk[base + 16 + ar];
    uint4 ev2 = epk[base + 32 + ar];
    uint4 ev3 = epk[base + 48 + ar];

    int r0 = (ap < 2) ? (int)ev0.y : (int)ev0.x;
    int r1 = (ap < 2) ? (int)ev1.y : (int)ev1.x;
    int r2 = (ap < 2) ? (int)ev2.y : (int)ev2.x;
    int r3 = (ap < 2) ? (int)ev3.y : (int)ev3.x;
    int half = (ap & 1) * 8;
    bf16x8 a00 = *reinterpret_cast<const bf16x8*>(xb + (size_t)r0 * 16 + half);
    bf16x8 a01 = *reinterpret_cast<const bf16x8*>(xb + (size_t)r1 * 16 + half);
    bf16x8 a02 = *reinterpret_cast<const bf16x8*>(xb + (size_t)r2 * 16 + half);
    bf16x8 a03 = *reinterpret_cast<const bf16x8*>(xb + (size_t)r3 * 16 + half);

    int d0 = __builtin_amdgcn_readfirstlane((int)ev0.y);

    bf16x8 Bf[8];
    const bf16x8* w1v = reinterpret_cast<const bf16x8*>(w1b);
    #pragma unroll
    for (int i = 0; i < 8; i++) Bf[i] = w1v[i * 64 + lane];

#define DO_TILE(EV, A0, TILE) do {                                             \
    bf16x8 a1 = (bf16x8)0;                                                     \
    if (ap == 0) {                                                             \
        a1[0] = (short)(EV.z & 0xffffu);                                       \
        a1[1] = (short)(EV.z >> 16);                                           \
        a1[2] = (short)(EV.w & 0xffffu);                                       \
        a1[3] = (short)(EV.w >> 16);                                           \
        a1[4] = (short)0x3f80;                                                 \
    }                                                                          \
    f32x4 C0 = {0.f, 0.f, 0.f, 0.f}, C1 = C0, C2 = C0, C3 = C0;                \
    C0 = __builtin_amdgcn_mfma_f32_16x16x32_bf16(A0, Bf[0], C0, 0, 0, 0);      \
    C0 = __builtin_amdgcn_mfma_f32_16x16x32_bf16(a1, Bf[1], C0, 0, 0, 0);      \
    C1 = __builtin_amdgcn_mfma_f32_16x16x32_bf16(A0, Bf[2], C1, 0, 0, 0);      \
    C1 = __builtin_amdgcn_mfma_f32_16x16x32_bf16(a1, Bf[3], C1, 0, 0, 0);      \
    C2 = __builtin_amdgcn_mfma_f32_16x16x32_bf16(A0, Bf[4], C2, 0, 0, 0);      \
    C2 = __builtin_amdgcn_mfma_f32_16x16x32_bf16(a1, Bf[5], C2, 0, 0, 0);      \
    C3 = __builtin_amdgcn_mfma_f32_16x16x32_bf16(A0, Bf[6], C3, 0, 0, 0);      \
    C3 = __builtin_amdgcn_mfma_f32_16x16x32_bf16(a1, Bf[7], C3, 0, 0, 0);      \
    int eoff = TILE * 16 + ap * 4;                                             \
    {                                                                          \
        unsigned lov = pk2(fmaxf(C0[0], 0.f), fmaxf(C0[1], 0.f));              \
        unsigned hiv = pk2(fmaxf(C0[2], 0.f), fmaxf(C0[3], 0.f));              \
        *reinterpret_cast<uint2*>(hb + (0 * 16 + ar) * 68 + eoff) = make_uint2(lov, hiv); \
    }                                                                          \
    {                                                                          \
        unsigned lov = pk2(fmaxf(C1[0], 0.f), fmaxf(C1[1], 0.f));              \
        unsigned hiv = pk2(fmaxf(C1[2], 0.f), fmaxf(C1[3], 0.f));              \
        *reinterpret_cast<uint2*>(hb + (1 * 16 + ar) * 68 + eoff) = make_uint2(lov, hiv); \
    }                                                                          \
    {                                                                          \
        unsigned lov = pk2(fmaxf(C2[0], 0.f), fmaxf(C2[1], 0.f));              \
        unsigned hiv = pk2(fmaxf(C2[2], 0.f), fmaxf(C2[3], 0.f));              \
        *reinterpret_cast<uint2*>(hb + (2 * 16 + ar) * 68 + eoff) = make_uint2(lov, hiv); \
    }                                                                          \
    {                                                                          \
        unsigned lov = pk2(fmaxf(C3[0], 0.f), fmaxf(C3[1], 0.f));              \
        unsigned hiv = pk2(fmaxf(C3[2], 0.f), fmaxf(C3[3], 0.f));              \
        *reinterpret_cast<uint2*>(hb + (3 * 16 + ar) * 68 + eoff) = make_uint2(lov, hiv); \
    }                                                                          \
} while (0)

    DO_TILE(ev0, a00, 0);
    DO_TILE(ev1, a01, 1);
    DO_TILE(ev2, a02, 2);
    DO_TILE(ev3, a03, 3);
#undef DO_TILE

    asm volatile("s_waitcnt lgkmcnt(0)" ::: "memory");
    __builtin_amdgcn_sched_barrier(0);

    int d = d0;
    int e = base;
    const int lim = base + 64;
    const unsigned short* hr = hb + lane * 68;
    while (e < lim) {
        int segend = off[d + 1];
        int eend = segend < lim ? segend : lim;
        float acc = 0.f;
        int i = e - base, iend = eend - base;
        for (; (i & 3) != 0 && i < iend; ++i) acc += bf2f(hr[i]);
        for (; i + 4 <= iend; i += 4) {
            uint2 u = *reinterpret_cast<const uint2*>(hr + i);
            acc += __uint_as_float(u.x << 16) + __uint_as_float(u.x & 0xffff0000u)
                 + __uint_as_float(u.y << 16) + __uint_as_float(u.y & 0xffff0000u);
        }
        for (; i < iend; ++i) acc += bf2f(hr[i]);
        unsafeAtomicAdd(&hag[(size_t)d * 64 + lane], acc);
        e = eend;
        if (segend <= lim) ++d;
    }
}

// ---------------------------------------------------------------------------
// node update (unchanged from R8)
// ---------------------------------------------------------------------------
__global__ __launch_bounds__(256) void node_mlp_kernel(
    const unsigned short* __restrict__ xb, unsigned short* __restrict__ xbn,
    float* __restrict__ hag, const int* __restrict__ off,
    const float* __restrict__ ew2, const float* __restrict__ eb2,
    const float* __restrict__ nw1t, const float* __restrict__ nb1,
    const float* __restrict__ nw2, const float* __restrict__ nb2,
    const float* __restrict__ fnw, const float* __restrict__ fnb,
    float* __restrict__ Hout, int writeH)
{
    int n = blockIdx.x * blockDim.x + threadIdx.x;
    if (n >= NN) return;
    float u[32];
    const uint4* xp = reinterpret_cast<const uint4*>(xb + n * 16);
    uint4 xa = xp[0], xbv = xp[1];
    {
        unsigned w[8] = {xa.x, xa.y, xa.z, xa.w, xbv.x, xbv.y, xbv.z, xbv.w};
        #pragma unroll
        for (int i = 0; i < 8; i++) {
            u[2 * i]     = __uint_as_float(w[i] << 16);
            u[2 * i + 1] = __uint_as_float(w[i] & 0xffff0000u);
        }
    }
    int dg = off[n + 1] - off[n];
    float inv = 1.0f / (float)(dg > 0 ? dg : 1);
    float bsc = (dg > 0) ? 1.0f : 0.0f;
    float tacc[16];
    #pragma unroll
    for (int k = 0; k < 16; k++) tacc[k] = 0.f;
    float4* hp4 = reinterpret_cast<float4*>(hag + (size_t)n * 64);
    #pragma unroll 1
    for (int j4 = 0; j4 < 16; j4++) {
        float4 hv = hp4[j4];
        int j = j4 * 4;
        #pragma unroll
        for (int k = 0; k < 16; k++) {
            tacc[k] += hv.x * ew2[(j + 0) * 16 + k];
            tacc[k] += hv.y * ew2[(j + 1) * 16 + k];
            tacc[k] += hv.z * ew2[(j + 2) * 16 + k];
            tacc[k] += hv.w * ew2[(j + 3) * 16 + k];
        }
    }
    float4 z = {0.f, 0.f, 0.f, 0.f};
    #pragma unroll
    for (int j4 = 0; j4 < 16; j4++) hp4[j4] = z;
    #pragma unroll
    for (int k = 0; k < 16; k++) u[16 + k] = bsc * eb2[k] + tacc[k] * inv;

    float o[16];
    #pragma unroll
    for (int k = 0; k < 16; k++) o[k] = nb2[k];
    #pragma unroll 1
    for (int j = 0; j < 64; j++) {
        float h = nb1[j];
        const float* wr = nw1t + j * 32;
        #pragma unroll
        for (int i = 0; i < 32; i++) h += u[i] * wr[i];
        h = fmaxf(h, 0.f);
        #pragma unroll
        for (int k = 0; k < 16; k++) o[k] += h * nw2[j * 16 + k];
    }
    unsigned pk[8];
    #pragma unroll
    for (int i = 0; i < 8; i++) pk[i] = pk2(o[2 * i], o[2 * i + 1]);
    uint4* xo = reinterpret_cast<uint4*>(xbn + n * 16);
    xo[0] = make_uint4(pk[0], pk[1], pk[2], pk[3]);
    xo[1] = make_uint4(pk[4], pk[5], pk[6], pk[7]);
    if (writeH) {
        float s = fnb[0];
        #pragma unroll
        for (int k = 0; k < 16; k++) s += o[k] * fnw[k];
        Hout[n] = s;
    }
}

extern "C" void kernel_launch(void* const* d_in, const int* in_sizes, int n_in,
                              void* d_out, int out_size, void* d_ws, size_t ws_size,
                              hipStream_t stream)
{
    const float* leak = (const float*)d_in[0];
    const float* pa   = (const float*)d_in[1];
    const int*   ei   = (const int*)d_in[2];
    const float* neww = (const float*)d_in[3];
    const float* newb = (const float*)d_in[4];
    const float* eeW  = (const float*)d_in[5];
    const float* eeB  = (const float*)d_in[6];
    const float* ew1  = (const float*)d_in[7];
    const float* eb1  = (const float*)d_in[8];
    const float* ew2  = (const float*)d_in[9];
    const float* eb2  = (const float*)d_in[10];
    const float* nw1  = (const float*)d_in[11];
    const float* nb1  = (const float*)d_in[12];
    const float* nw2  = (const float*)d_in[13];
    const float* nb2  = (const float*)d_in[14];
    const float* fnw  = (const float*)d_in[15];
    const float* fnb  = (const float*)d_in[16];
    const float* few  = (const float*)d_in[17];
    const float* feb  = (const float*)d_in[18];

    char* wsb = (char*)d_ws;
    float*          hag   = (float*)(wsb + B_HAG);
    float*          qw    = (float*)(wsb + B_QW);
    float*          w1tn  = (float*)(wsb + B_W1TN);
    unsigned short* w1b   = (unsigned short*)(wsb + B_W1B);
    unsigned short* xb0   = (unsigned short*)(wsb + B_XB0);
    unsigned short* xb1   = (unsigned short*)(wsb + B_XB1);
    uint4*          epk   = (uint4*)(wsb + B_EPK);
    int*            off   = (int*)(wsb + B_OFF);
    int*            bcnt  = (int*)(wsb + B_BCNT);
    int*            gbase = (int*)(wsb + B_BASE);

    float* H = (float*)d_out;
    float* q = (float*)d_out + NN;
    const int* dstp = ei + NE;

    prep_kernel<<<16, 256, 0, stream>>>(ew1, eb1, nw1, eeW, eeB, few, feb,
                                        w1b, w1tn, qw);
    node_init_kernel<<<(NN + 255) / 256, 256, 0, stream>>>(leak, neww, newb, xb0, hag);
    bucket_count_kernel<<<CBLK, 1024, 0, stream>>>(dstp, bcnt);
    bucket_scan_kernel<<<1, 512, 0, stream>>>(bcnt, gbase);
    bucket_scatter_kernel<<<CBLK, 1024, 0, stream>>>(ei, pa, bcnt, qw, q, epk);
    fine_sort_kernel<<<NB, 1024, 0, stream>>>(gbase, epk, off);

    unsigned short* xcur = xb0;
    unsigned short* xnxt = xb1;
    for (int l = 0; l < 3; l++) {
        edge_mfma_kernel<<<NE / 256, 256, 0, stream>>>(
            xcur, epk, off, w1b + l * 4096, hag);
        node_mlp_kernel<<<(NN + 255) / 256, 256, 0, stream>>>(
            xcur, xnxt, hag, off, ew2 + l * 1024, eb2 + l * 16,
            w1tn + l * 2048, nb1 + l * 64, nw2 + l * 1024, nb2 + l * 16,
            fnw, fnb, H, (l == 2) ? 1 : 0);
        unsigned short* tmp = xcur; xcur = xnxt; xnxt = tmp;
    }
}